// Round 1
// baseline (1107.211 us; speedup 1.0000x reference)
//
#include <hip/hip_runtime.h>
#include <cmath>

// Problem constants (fixed by setup_inputs)
static constexpr int SEQ = 1024;
static constexpr int DIM = 1024;
static constexpr int NH  = 16;
static constexpr int DH  = 64;   // head dim
static constexpr int WB  = 2;    // batch
static constexpr int ROWS = WB * SEQ;           // 2048
__device__ static constexpr double D_EPS = 1e-7;

// ---------------- reductions ----------------
__device__ __forceinline__ double wsum64(double v) {
#pragma unroll
  for (int m = 32; m >= 1; m >>= 1) v += __shfl_xor(v, m, 64);
  return v;
}

// ---------------- K1/K7: tangent-space layernorm chain ----------------
// out = logmap0(project(expmap0(LN(logmap0(x,c)), c)), c)   (per row of DIM)
__global__ __launch_bounds__(256) void ln_tan_kernel(
    const float* __restrict__ xin, const float* __restrict__ cb,
    const float* __restrict__ gamma, const float* __restrict__ beta,
    float* __restrict__ out) {
  __shared__ double sh[2][4];
  const int row = blockIdx.x;
  const int b = row / SEQ;
  const float* xr = xin + (size_t)row * DIM;
  const int t = threadIdx.x;
  float xv[4];
  double s0 = 0.0, s1 = 0.0;
#pragma unroll
  for (int i = 0; i < 4; i++) {
    xv[i] = xr[t + 256 * i];
    s0 += (double)xv[i];
    s1 += (double)xv[i] * (double)xv[i];
  }
  s0 = wsum64(s0); s1 = wsum64(s1);
  const int wid = t >> 6, lane = t & 63;
  if (lane == 0) { sh[0][wid] = s0; sh[1][wid] = s1; }
  __syncthreads();
  s0 = sh[0][0] + sh[0][1] + sh[0][2] + sh[0][3];
  s1 = sh[1][0] + sh[1][1] + sh[1][2] + sh[1][3];

  const double cc  = (double)cb[b];
  const double sqc = fmax(sqrt(cc), D_EPS);
  const double xn  = sqrt(s1);
  double a = 0.0;
  if (xn >= D_EPS) a = atanh(fmin(xn, 1.0 - D_EPS)) / sqc / fmax(xn, D_EPS);
  const double mu   = a * s0 / (double)DIM;
  const double var  = a * a * s1 / (double)DIM - mu * mu;
  const double invs = 1.0 / sqrt(var + 1e-6);

  double tv[4]; double s2 = 0.0;
#pragma unroll
  for (int i = 0; i < 4; i++) {
    const int col = t + 256 * i;
    tv[i] = (a * (double)xv[i] - mu) * invs * (double)gamma[col] + (double)beta[col];
    s2 += tv[i] * tv[i];
  }
  s2 = wsum64(s2);
  __syncthreads();
  if (lane == 0) sh[0][wid] = s2;
  __syncthreads();
  s2 = sh[0][0] + sh[0][1] + sh[0][2] + sh[0][3];

  const double tn = sqrt(s2);
  double C = 0.0;
  if (tn >= D_EPS) {
    const double safe_t = fmax(tn, D_EPS);
    const double mag2 = tanh(sqc * safe_t) / sqc;   // expmap0 magnitude
    const double en = mag2 * (tn / safe_t);         // ||e|| analytic
    const double pn = fmax(en, D_EPS);
    const double f  = (pn >= 1.0) ? (1.0 - D_EPS) / pn : 1.0;   // project
    const double yn = en * f;
    if (yn >= D_EPS) {
      const double mag3 = atanh(fmin(yn, 1.0 - D_EPS)) / sqc;   // logmap0
      C = (mag2 / safe_t) * f * (mag3 / fmax(yn, D_EPS));
    }
  }
  float* orow = out + (size_t)row * DIM;
#pragma unroll
  for (int i = 0; i < 4; i++) orow[t + 256 * i] = (float)(tv[i] * C);
}

// ---------------- K6/K9: out = mobius_add(xb, expmap0(tg, c), c) ----------------
__global__ __launch_bounds__(256) void expmobius_kernel(
    const float* __restrict__ xb, const float* __restrict__ tg,
    const float* __restrict__ cb, float* __restrict__ out) {
  __shared__ double sh[3][4];
  const int row = blockIdx.x;
  const int b = row / SEQ;
  const float* xr = xb + (size_t)row * DIM;
  const float* tr = tg + (size_t)row * DIM;
  const int t = threadIdx.x;
  float xv[4], tv[4];
  double sx2 = 0.0, st2 = 0.0, sxt = 0.0;
#pragma unroll
  for (int i = 0; i < 4; i++) {
    xv[i] = xr[t + 256 * i];
    tv[i] = tr[t + 256 * i];
    sx2 += (double)xv[i] * (double)xv[i];
    st2 += (double)tv[i] * (double)tv[i];
    sxt += (double)xv[i] * (double)tv[i];
  }
  sx2 = wsum64(sx2); st2 = wsum64(st2); sxt = wsum64(sxt);
  const int wid = t >> 6, lane = t & 63;
  if (lane == 0) { sh[0][wid] = sx2; sh[1][wid] = st2; sh[2][wid] = sxt; }
  __syncthreads();
  sx2 = sh[0][0] + sh[0][1] + sh[0][2] + sh[0][3];
  st2 = sh[1][0] + sh[1][1] + sh[1][2] + sh[1][3];
  sxt = sh[2][0] + sh[2][1] + sh[2][2] + sh[2][3];

  const double cc  = (double)cb[b];
  const double sqc = fmax(sqrt(cc), D_EPS);
  const double tn = sqrt(st2);
  double s = 0.0;
  if (tn >= D_EPS) {
    const double safe = fmax(tn, D_EPS);
    const double mag = tanh(sqc * safe) / sqc;      // expmap0
    const double en = mag * (tn / safe);
    const double pn = fmax(en, D_EPS);
    const double f  = (pn >= 1.0) ? (1.0 - D_EPS) / pn : 1.0;  // project
    s = (mag / safe) * f;                            // y_i = s * t_i
  }
  const double x2 = sx2, y2 = s * s * st2, xy = s * sxt;
  const double P   = 1.0 + 2.0 * cc * xy + cc * y2;
  const double Q   = 1.0 - cc * x2;
  const double den = fmax(1.0 + 2.0 * cc * xy + cc * cc * x2 * y2, D_EPS);
  const double num2 = P * P * x2 + Q * Q * y2 + 2.0 * P * Q * xy;
  const double rn  = sqrt(fmax(num2, 0.0)) / den;
  const double pn2 = fmax(rn, D_EPS);
  const double pf  = (pn2 >= 1.0) ? (1.0 - D_EPS) / pn2 : 1.0;  // project
  const double Pd = (P / den) * pf;
  const double Qd = (Q / den) * pf * s;
  float* orow = out + (size_t)row * DIM;
#pragma unroll
  for (int i = 0; i < 4; i++)
    orow[t + 256 * i] = (float)(Pd * (double)xv[i] + Qd * (double)tv[i]);
}

// ---------------- K3: RoPE + expmap0 per head, in place on q and k ----------------
__global__ __launch_bounds__(256) void rope_expmap_kernel(
    float* __restrict__ q, float* __restrict__ k,
    const float* __restrict__ freqs, const float* __restrict__ cb) {
  const int row = blockIdx.x;           // b*SEQ + n
  const int b = row / SEQ, n = row % SEQ;
  const int t = threadIdx.x;
  const int h = t >> 4, j = t & 15;
  const int p1 = j, p2 = j + 16;        // pair indices in [0,32)
  const double f1 = (double)freqs[n * (DH / 2) + p1];
  const double f2 = (double)freqs[n * (DH / 2) + p2];
  const double c1 = cos(f1), s1 = sin(f1);
  const double c2 = cos(f2), s2 = sin(f2);
  const double cc  = (double)cb[b];
  const double sqc = fmax(sqrt(cc), D_EPS);
  const size_t base = (size_t)row * DIM + (size_t)h * DH;
  float* arrs[2] = {q, k};
#pragma unroll
  for (int a = 0; a < 2; a++) {
    float* p = arrs[a] + base;
    const double xr1 = p[p1], xi1 = p[p1 + 32];
    const double xr2 = p[p2], xi2 = p[p2 + 32];
    const double r1 = xr1 * c1 - xi1 * s1, i1 = xr1 * s1 + xi1 * c1;
    const double r2 = xr2 * c2 - xi2 * s2, i2 = xr2 * s2 + xi2 * c2;
    double nrm2 = r1 * r1 + i1 * i1 + r2 * r2 + i2 * i2;
#pragma unroll
    for (int m = 8; m >= 1; m >>= 1) nrm2 += __shfl_xor(nrm2, m, 16);
    const double vn = sqrt(nrm2);
    double sc = 0.0;
    if (vn >= D_EPS) {
      const double safe = fmax(vn, D_EPS);
      const double mag = tanh(sqc * safe) / sqc;
      const double en = mag * (vn / safe);
      const double pn = fmax(en, D_EPS);
      const double f  = (pn >= 1.0) ? (1.0 - D_EPS) / pn : 1.0;
      sc = (mag / safe) * f;
    }
    p[p1] = (float)(r1 * sc); p[p1 + 32] = (float)(i1 * sc);
    p[p2] = (float)(r2 * sc); p[p2 + 32] = (float)(i2 * sc);
  }
}

// ---------------- K4: sliding-window Poincare attention ----------------
// 32 lanes per (b,h,n); lane w handles key at position n-31+w.
__global__ __launch_bounds__(256) void attn_kernel(
    const float* __restrict__ qh, const float* __restrict__ kh,
    const float* __restrict__ v, const float* __restrict__ cb,
    const float* __restrict__ geo, float* __restrict__ out) {
  __shared__ float qs[8][DH];
  const int g = threadIdx.x >> 5;       // group in block: 0..7
  const int w = threadIdx.x & 31;       // lane in group
  const int gid = blockIdx.x * 8 + g;   // (b*NH + h)*SEQ + n
  const int n = gid & (SEQ - 1);
  const int bh = gid >> 10;
  const int h = bh & (NH - 1);
  const int b = bh >> 4;
  const size_t qbase = ((size_t)(b * SEQ + n)) * DIM + (size_t)h * DH;
  qs[g][w] = qh[qbase + w];
  qs[g][w + 32] = qh[qbase + w + 32];
  __syncthreads();

  const double cc  = (double)cb[b];
  const double sqc = fmax(sqrt(cc), D_EPS);
  // ||q||^2 (same for all lanes of the group)
  double q2p = (double)qs[g][w] * qs[g][w] + (double)qs[g][w + 32] * qs[g][w + 32];
#pragma unroll
  for (int m = 16; m >= 1; m >>= 1) q2p += __shfl_xor(q2p, m, 32);
  const double a2 = q2p;

  const int msrc = n - 31 + w;
  double y2 = 0.0, qy = 0.0;
  if (msrc >= 0) {
    const float* kr = kh + ((size_t)(b * SEQ + msrc)) * DIM + (size_t)h * DH;
#pragma unroll 8
    for (int d = 0; d < DH; d++) {
      const double kv = (double)kr[d];
      y2 += kv * kv;
      qy += (double)qs[g][d] * kv;
    }
  }
  const double ay = -qy;  // mobius_add(-q, k)
  const double P = 1.0 + 2.0 * cc * ay + cc * y2;
  const double Q = 1.0 - cc * a2;
  const double den = fmax(1.0 + 2.0 * cc * ay + cc * cc * a2 * y2, D_EPS);
  const double num2 = P * P * a2 + Q * Q * y2 + 2.0 * P * Q * ay;
  const double rn = sqrt(fmax(num2, 0.0)) / den;
  const double pn = fmax(rn, D_EPS);
  const double addn = (pn >= 1.0) ? (1.0 - D_EPS) * (rn / pn) : rn;  // project
  const double arg = fmin(sqc * addn, 1.0 - D_EPS);
  const double dist = 2.0 * atanh(arg) / sqc;
  const double logit = -(double)geo[h] * dist;

  // softmax over 32 window positions
  double mx = logit;
#pragma unroll
  for (int m = 16; m >= 1; m >>= 1) mx = fmax(mx, __shfl_xor(mx, m, 32));
  const double e = exp(logit - mx);
  double se = e;
#pragma unroll
  for (int m = 16; m >= 1; m >>= 1) se += __shfl_xor(se, m, 32);
  const double p = e / se;

  // PV: lane w accumulates output dims w and w+32
  double acc1 = 0.0, acc2 = 0.0;
  for (int wp = 0; wp < 32; wp++) {
    const double pw = __shfl(p, wp, 32);
    const int mp = n - 31 + wp;
    if (mp >= 0) {
      const float* vr = v + ((size_t)(b * SEQ + mp)) * DIM + (size_t)h * DH;
      acc1 += pw * (double)vr[w];
      acc2 += pw * (double)vr[w + 32];
    }
  }
  out[qbase + w] = (float)acc1;
  out[qbase + w + 32] = (float)acc2;
}

// ---------------- generic fp32 GEMM: C = A[MxK] @ W[KxN] + bias, opt. GELU ----------------
__device__ __forceinline__ float gelu_tanh(float x) {
  const float x3 = x * x * x;
  return 0.5f * x * (1.0f + tanhf(0.7978845608028654f * (x + 0.044715f * x3)));
}

template <int EPI>
__global__ __launch_bounds__(256) void gemm_kernel(
    const float* __restrict__ A, const float* __restrict__ W,
    const float* __restrict__ bias, float* __restrict__ C,
    int M, int K, int Nc) {
  __shared__ float As[16][64];   // As[k][m]
  __shared__ float Bs[16][64];   // Bs[k][n]
  const int t = threadIdx.x;
  const int tm = t >> 4, tn = t & 15;
  const int m0 = blockIdx.y << 6, n0 = blockIdx.x << 6;
  const int ar = t >> 2, ac = (t & 3) << 2;
  const int br = t >> 4, bc = (t & 15) << 2;
  const float* Ag = A + (size_t)(m0 + ar) * K + ac;
  const float* Bg = W + (size_t)br * Nc + n0 + bc;
  float acc[4][4] = {{0.f, 0.f, 0.f, 0.f}, {0.f, 0.f, 0.f, 0.f},
                     {0.f, 0.f, 0.f, 0.f}, {0.f, 0.f, 0.f, 0.f}};
  for (int kt = 0; kt < K; kt += 16) {
    const float4 av = *(const float4*)(Ag + kt);
    const float4 bv = *(const float4*)(Bg + (size_t)kt * Nc);
    __syncthreads();
    As[ac + 0][ar] = av.x; As[ac + 1][ar] = av.y;
    As[ac + 2][ar] = av.z; As[ac + 3][ar] = av.w;
    *(float4*)&Bs[br][bc] = bv;
    __syncthreads();
#pragma unroll
    for (int kk = 0; kk < 16; kk++) {
      const float4 aa = *(const float4*)&As[kk][tm << 2];
      const float4 bb = *(const float4*)&Bs[kk][tn << 2];
      acc[0][0] += aa.x * bb.x; acc[0][1] += aa.x * bb.y; acc[0][2] += aa.x * bb.z; acc[0][3] += aa.x * bb.w;
      acc[1][0] += aa.y * bb.x; acc[1][1] += aa.y * bb.y; acc[1][2] += aa.y * bb.z; acc[1][3] += aa.y * bb.w;
      acc[2][0] += aa.z * bb.x; acc[2][1] += aa.z * bb.y; acc[2][2] += aa.z * bb.z; acc[2][3] += aa.z * bb.w;
      acc[3][0] += aa.w * bb.x; acc[3][1] += aa.w * bb.y; acc[3][2] += aa.w * bb.z; acc[3][3] += aa.w * bb.w;
    }
  }
#pragma unroll
  for (int i = 0; i < 4; i++) {
    const int row = m0 + (tm << 2) + i;
    const int col = n0 + (tn << 2);
    float4 r;
    r.x = acc[i][0] + bias[col + 0];
    r.y = acc[i][1] + bias[col + 1];
    r.z = acc[i][2] + bias[col + 2];
    r.w = acc[i][3] + bias[col + 3];
    if (EPI == 1) { r.x = gelu_tanh(r.x); r.y = gelu_tanh(r.y); r.z = gelu_tanh(r.z); r.w = gelu_tanh(r.w); }
    *(float4*)&C[(size_t)row * Nc + col] = r;
  }
}

extern "C" void kernel_launch(void* const* d_in, const int* in_sizes, int n_in,
                              void* d_out, int out_size, void* d_ws, size_t ws_size,
                              hipStream_t stream) {
  const float* x     = (const float*)d_in[0];
  const float* freqs = (const float*)d_in[1];
  const float* c     = (const float*)d_in[2];
  const float* Wq = (const float*)d_in[3];  const float* bq = (const float*)d_in[4];
  const float* Wk = (const float*)d_in[5];  const float* bk = (const float*)d_in[6];
  const float* Wv = (const float*)d_in[7];  const float* bv = (const float*)d_in[8];
  const float* Wo = (const float*)d_in[9];  const float* bo = (const float*)d_in[10];
  const float* W1 = (const float*)d_in[11]; const float* b1 = (const float*)d_in[12];
  const float* W2 = (const float*)d_in[13]; const float* b2 = (const float*)d_in[14];
  const float* g1 = (const float*)d_in[15]; const float* be1 = (const float*)d_in[16];
  const float* g2 = (const float*)d_in[17]; const float* be2 = (const float*)d_in[18];
  const float* geo = (const float*)d_in[19];
  float* out = (float*)d_out;
  float* ws = (float*)d_ws;

  const size_t SZ = (size_t)WB * SEQ * DIM;   // 2M floats
  float* x_tan = ws + 0 * SZ;   // later reused as ffn_tan
  float* qb    = ws + 1 * SZ;   // q -> q_hyp (in place) -> later t2
  float* kb    = ws + 2 * SZ;   // k -> k_hyp (in place)
  float* vb    = ws + 3 * SZ;   // v -> later ao_proj
  float* att   = ws + 4 * SZ;
  float* x_att = ws + 5 * SZ;
  float* h1    = ws + 6 * SZ;   // 4*SZ (FFN hidden)

  // 1. tangent LN1
  ln_tan_kernel<<<ROWS, 256, 0, stream>>>(x, c, g1, be1, x_tan);
  // 2. QKV projections
  dim3 gq(DIM / 64, ROWS / 64);
  gemm_kernel<0><<<gq, 256, 0, stream>>>(x_tan, Wq, bq, qb, ROWS, DIM, DIM);
  gemm_kernel<0><<<gq, 256, 0, stream>>>(x_tan, Wk, bk, kb, ROWS, DIM, DIM);
  gemm_kernel<0><<<gq, 256, 0, stream>>>(x_tan, Wv, bv, vb, ROWS, DIM, DIM);
  // 3. RoPE + expmap0 (q,k in place)
  rope_expmap_kernel<<<ROWS, 256, 0, stream>>>(qb, kb, freqs, c);
  // 4. sliding-window Poincare attention
  attn_kernel<<<WB * NH * SEQ / 8, 256, 0, stream>>>(qb, kb, vb, c, geo, att);
  // 5. output projection (ao_proj into vb; v is dead)
  gemm_kernel<0><<<gq, 256, 0, stream>>>(att, Wo, bo, vb, ROWS, DIM, DIM);
  // 6. x_att = mobius_add(x, expmap0(ao_proj))
  expmobius_kernel<<<ROWS, 256, 0, stream>>>(x, vb, c, x_att);
  // 7. tangent LN2 (t2 into qb)
  ln_tan_kernel<<<ROWS, 256, 0, stream>>>(x_att, c, g2, be2, qb);
  // 8. FFN up + gelu
  dim3 gup(4 * DIM / 64, ROWS / 64);
  gemm_kernel<1><<<gup, 256, 0, stream>>>(qb, W1, b1, h1, ROWS, DIM, 4 * DIM);
  // 9. FFN down (ffn_tan into x_tan)
  dim3 gdn(DIM / 64, ROWS / 64);
  gemm_kernel<0><<<gdn, 256, 0, stream>>>(h1, W2, b2, x_tan, ROWS, 4 * DIM, DIM);
  // 10. out = mobius_add(x_att, expmap0(ffn_tan))
  expmobius_kernel<<<ROWS, 256, 0, stream>>>(x_att, x_tan, c, out);
  (void)in_sizes; (void)n_in; (void)out_size; (void)ws_size;
}

// Round 2
// 903.830 us; speedup vs baseline: 1.2250x; 1.2250x over previous
//
#include <hip/hip_runtime.h>
#include <cmath>

// Problem constants (fixed by setup_inputs)
static constexpr int SEQ = 1024;
static constexpr int DIM = 1024;
static constexpr int NH  = 16;
static constexpr int DH  = 64;   // head dim
static constexpr int WB  = 2;    // batch
static constexpr int ROWS = WB * SEQ;           // 2048
__device__ static constexpr double D_EPS = 1e-7;

// ---------------- reductions ----------------
__device__ __forceinline__ double wsum64(double v) {
#pragma unroll
  for (int m = 32; m >= 1; m >>= 1) v += __shfl_xor(v, m, 64);
  return v;
}

// ---------------- tangent-space layernorm chain ----------------
// out = logmap0(project(expmap0(LN(logmap0(x,c)), c)), c)   (per row of DIM)
__global__ __launch_bounds__(256) void ln_tan_kernel(
    const float* __restrict__ xin, const float* __restrict__ cb,
    const float* __restrict__ gamma, const float* __restrict__ beta,
    float* __restrict__ out) {
  __shared__ double sh[2][4];
  const int row = blockIdx.x;
  const int b = row / SEQ;
  const float* xr = xin + (size_t)row * DIM;
  const int t = threadIdx.x;
  float xv[4];
  double s0 = 0.0, s1 = 0.0;
#pragma unroll
  for (int i = 0; i < 4; i++) {
    xv[i] = xr[t + 256 * i];
    s0 += (double)xv[i];
    s1 += (double)xv[i] * (double)xv[i];
  }
  s0 = wsum64(s0); s1 = wsum64(s1);
  const int wid = t >> 6, lane = t & 63;
  if (lane == 0) { sh[0][wid] = s0; sh[1][wid] = s1; }
  __syncthreads();
  s0 = sh[0][0] + sh[0][1] + sh[0][2] + sh[0][3];
  s1 = sh[1][0] + sh[1][1] + sh[1][2] + sh[1][3];

  const double cc  = (double)cb[b];
  const double sqc = fmax(sqrt(cc), D_EPS);
  const double xn  = sqrt(s1);
  double a = 0.0;
  if (xn >= D_EPS) a = atanh(fmin(xn, 1.0 - D_EPS)) / sqc / fmax(xn, D_EPS);
  const double mu   = a * s0 / (double)DIM;
  const double var  = a * a * s1 / (double)DIM - mu * mu;
  const double invs = 1.0 / sqrt(var + 1e-6);

  double tv[4]; double s2 = 0.0;
#pragma unroll
  for (int i = 0; i < 4; i++) {
    const int col = t + 256 * i;
    tv[i] = (a * (double)xv[i] - mu) * invs * (double)gamma[col] + (double)beta[col];
    s2 += tv[i] * tv[i];
  }
  s2 = wsum64(s2);
  __syncthreads();
  if (lane == 0) sh[0][wid] = s2;
  __syncthreads();
  s2 = sh[0][0] + sh[0][1] + sh[0][2] + sh[0][3];

  const double tn = sqrt(s2);
  double C = 0.0;
  if (tn >= D_EPS) {
    const double safe_t = fmax(tn, D_EPS);
    const double mag2 = tanh(sqc * safe_t) / sqc;   // expmap0 magnitude
    const double en = mag2 * (tn / safe_t);         // ||e|| analytic
    const double pn = fmax(en, D_EPS);
    const double f  = (pn >= 1.0) ? (1.0 - D_EPS) / pn : 1.0;   // project
    const double yn = en * f;
    if (yn >= D_EPS) {
      const double mag3 = atanh(fmin(yn, 1.0 - D_EPS)) / sqc;   // logmap0
      C = (mag2 / safe_t) * f * (mag3 / fmax(yn, D_EPS));
    }
  }
  float* orow = out + (size_t)row * DIM;
#pragma unroll
  for (int i = 0; i < 4; i++) orow[t + 256 * i] = (float)(tv[i] * C);
}

// ---------------- out = mobius_add(xb, expmap0(p0+p1+bias, c), c) ----------------
// (tangent input arrives as two split-K GEMM partials + bias, summed in fp64)
__global__ __launch_bounds__(256) void expmobius_parts_kernel(
    const float* __restrict__ xb, const float* __restrict__ p0,
    const float* __restrict__ p1, const float* __restrict__ bias,
    const float* __restrict__ cb, float* __restrict__ out) {
  __shared__ double sh[3][4];
  const int row = blockIdx.x;
  const int b = row / SEQ;
  const float* xr = xb + (size_t)row * DIM;
  const float* p0r = p0 + (size_t)row * DIM;
  const float* p1r = p1 + (size_t)row * DIM;
  const int t = threadIdx.x;
  float xv[4];
  double tv[4];
  double sx2 = 0.0, st2 = 0.0, sxt = 0.0;
#pragma unroll
  for (int i = 0; i < 4; i++) {
    const int col = t + 256 * i;
    xv[i] = xr[col];
    tv[i] = (double)p0r[col] + (double)p1r[col] + (double)bias[col];
    sx2 += (double)xv[i] * (double)xv[i];
    st2 += tv[i] * tv[i];
    sxt += (double)xv[i] * tv[i];
  }
  sx2 = wsum64(sx2); st2 = wsum64(st2); sxt = wsum64(sxt);
  const int wid = t >> 6, lane = t & 63;
  if (lane == 0) { sh[0][wid] = sx2; sh[1][wid] = st2; sh[2][wid] = sxt; }
  __syncthreads();
  sx2 = sh[0][0] + sh[0][1] + sh[0][2] + sh[0][3];
  st2 = sh[1][0] + sh[1][1] + sh[1][2] + sh[1][3];
  sxt = sh[2][0] + sh[2][1] + sh[2][2] + sh[2][3];

  const double cc  = (double)cb[b];
  const double sqc = fmax(sqrt(cc), D_EPS);
  const double tn = sqrt(st2);
  double s = 0.0;
  if (tn >= D_EPS) {
    const double safe = fmax(tn, D_EPS);
    const double mag = tanh(sqc * safe) / sqc;      // expmap0
    const double en = mag * (tn / safe);
    const double pn = fmax(en, D_EPS);
    const double f  = (pn >= 1.0) ? (1.0 - D_EPS) / pn : 1.0;  // project
    s = (mag / safe) * f;                            // y_i = s * t_i
  }
  const double x2 = sx2, y2 = s * s * st2, xy = s * sxt;
  const double P   = 1.0 + 2.0 * cc * xy + cc * y2;
  const double Q   = 1.0 - cc * x2;
  const double den = fmax(1.0 + 2.0 * cc * xy + cc * cc * x2 * y2, D_EPS);
  const double num2 = P * P * x2 + Q * Q * y2 + 2.0 * P * Q * xy;
  const double rn  = sqrt(fmax(num2, 0.0)) / den;
  const double pn2 = fmax(rn, D_EPS);
  const double pf  = (pn2 >= 1.0) ? (1.0 - D_EPS) / pn2 : 1.0;  // project
  const double Pd = (P / den) * pf;
  const double Qd = (Q / den) * pf * s;
  float* orow = out + (size_t)row * DIM;
#pragma unroll
  for (int i = 0; i < 4; i++)
    orow[t + 256 * i] = (float)(Pd * (double)xv[i] + Qd * tv[i]);
}

// ---------------- RoPE + expmap0 per head, in place on q and k ----------------
__global__ __launch_bounds__(256) void rope_expmap_kernel(
    float* __restrict__ q, float* __restrict__ k,
    const float* __restrict__ freqs, const float* __restrict__ cb) {
  const int row = blockIdx.x;           // b*SEQ + n
  const int b = row / SEQ, n = row % SEQ;
  const int t = threadIdx.x;
  const int h = t >> 4, j = t & 15;
  const int p1 = j, p2 = j + 16;        // pair indices in [0,32)
  const double f1 = (double)freqs[n * (DH / 2) + p1];
  const double f2 = (double)freqs[n * (DH / 2) + p2];
  const double c1 = cos(f1), s1 = sin(f1);
  const double c2 = cos(f2), s2 = sin(f2);
  const double cc  = (double)cb[b];
  const double sqc = fmax(sqrt(cc), D_EPS);
  const size_t base = (size_t)row * DIM + (size_t)h * DH;
  float* arrs[2] = {q, k};
#pragma unroll
  for (int a = 0; a < 2; a++) {
    float* p = arrs[a] + base;
    const double xr1 = p[p1], xi1 = p[p1 + 32];
    const double xr2 = p[p2], xi2 = p[p2 + 32];
    const double r1 = xr1 * c1 - xi1 * s1, i1 = xr1 * s1 + xi1 * c1;
    const double r2 = xr2 * c2 - xi2 * s2, i2 = xr2 * s2 + xi2 * c2;
    double nrm2 = r1 * r1 + i1 * i1 + r2 * r2 + i2 * i2;
#pragma unroll
    for (int m = 8; m >= 1; m >>= 1) nrm2 += __shfl_xor(nrm2, m, 16);
    const double vn = sqrt(nrm2);
    double sc = 0.0;
    if (vn >= D_EPS) {
      const double safe = fmax(vn, D_EPS);
      const double mag = tanh(sqc * safe) / sqc;
      const double en = mag * (vn / safe);
      const double pn = fmax(en, D_EPS);
      const double f  = (pn >= 1.0) ? (1.0 - D_EPS) / pn : 1.0;
      sc = (mag / safe) * f;
    }
    p[p1] = (float)(r1 * sc); p[p1 + 32] = (float)(i1 * sc);
    p[p2] = (float)(r2 * sc); p[p2 + 32] = (float)(i2 * sc);
  }
}

// ---------------- sliding-window Poincare attention ----------------
__global__ __launch_bounds__(256) void attn_kernel(
    const float* __restrict__ qh, const float* __restrict__ kh,
    const float* __restrict__ v, const float* __restrict__ cb,
    const float* __restrict__ geo, float* __restrict__ out) {
  __shared__ float qs[8][DH];
  const int g = threadIdx.x >> 5;       // group in block: 0..7
  const int w = threadIdx.x & 31;       // lane in group
  const int gid = blockIdx.x * 8 + g;   // (b*NH + h)*SEQ + n
  const int n = gid & (SEQ - 1);
  const int bh = gid >> 10;
  const int h = bh & (NH - 1);
  const int b = bh >> 4;
  const size_t qbase = ((size_t)(b * SEQ + n)) * DIM + (size_t)h * DH;
  qs[g][w] = qh[qbase + w];
  qs[g][w + 32] = qh[qbase + w + 32];
  __syncthreads();

  const double cc  = (double)cb[b];
  const double sqc = fmax(sqrt(cc), D_EPS);
  double q2p = (double)qs[g][w] * qs[g][w] + (double)qs[g][w + 32] * qs[g][w + 32];
#pragma unroll
  for (int m = 16; m >= 1; m >>= 1) q2p += __shfl_xor(q2p, m, 32);
  const double a2 = q2p;

  const int msrc = n - 31 + w;
  double y2 = 0.0, qy = 0.0;
  if (msrc >= 0) {
    const float* kr = kh + ((size_t)(b * SEQ + msrc)) * DIM + (size_t)h * DH;
#pragma unroll 8
    for (int d = 0; d < DH; d++) {
      const double kv = (double)kr[d];
      y2 += kv * kv;
      qy += (double)qs[g][d] * kv;
    }
  }
  const double ay = -qy;  // mobius_add(-q, k)
  const double P = 1.0 + 2.0 * cc * ay + cc * y2;
  const double Q = 1.0 - cc * a2;
  const double den = fmax(1.0 + 2.0 * cc * ay + cc * cc * a2 * y2, D_EPS);
  const double num2 = P * P * a2 + Q * Q * y2 + 2.0 * P * Q * ay;
  const double rn = sqrt(fmax(num2, 0.0)) / den;
  const double pn = fmax(rn, D_EPS);
  const double addn = (pn >= 1.0) ? (1.0 - D_EPS) * (rn / pn) : rn;  // project
  const double arg = fmin(sqc * addn, 1.0 - D_EPS);
  const double dist = 2.0 * atanh(arg) / sqc;
  const double logit = -(double)geo[h] * dist;

  double mx = logit;
#pragma unroll
  for (int m = 16; m >= 1; m >>= 1) mx = fmax(mx, __shfl_xor(mx, m, 32));
  const double e = exp(logit - mx);
  double se = e;
#pragma unroll
  for (int m = 16; m >= 1; m >>= 1) se += __shfl_xor(se, m, 32);
  const double p = e / se;

  double acc1 = 0.0, acc2 = 0.0;
  for (int wp = 0; wp < 32; wp++) {
    const double pw = __shfl(p, wp, 32);
    const int mp = n - 31 + wp;
    if (mp >= 0) {
      const float* vr = v + ((size_t)(b * SEQ + mp)) * DIM + (size_t)h * DH;
      acc1 += pw * (double)vr[w];
      acc2 += pw * (double)vr[w + 32];
    }
  }
  out[qbase + w] = (float)acc1;
  out[qbase + w + 32] = (float)acc2;
}

// ---------------- fp32 GEMM epilogue helper ----------------
__device__ __forceinline__ float gelu_tanh(float x) {
  const float x3 = x * x * x;
  return 0.5f * x * (1.0f + tanhf(0.7978845608028654f * (x + 0.044715f * x3)));
}

// ================= gemm128: 128x128 tile, 256 thr, 8x8/thread =================
// C[M,N] = A[M,Kld](cols k0..) @ W[*,N] + bias, optional GELU. K multiple of 16.
template <int EPI>
__global__ __launch_bounds__(256) void gemm128(
    const float* __restrict__ A, int Kld,
    const float* __restrict__ W, const float* __restrict__ bias,
    float* __restrict__ C, int N, int klen) {
  __shared__ float As[16][128];
  __shared__ float Bs[16][128];
  const int t = threadIdx.x;
  const int m0 = blockIdx.y << 7, n0 = blockIdx.x << 7;
  // staging indices
  const int ar = t >> 1, ah = (t & 1) << 3;          // A: row, k-half
  const int br = t >> 4, bc = (t & 15) << 3;         // B: k-row, col
  const float* Ag = A + (size_t)(m0 + ar) * Kld + ah;
  const float* Bg = W + (size_t)br * N + n0 + bc;
  // compute indices
  const int tm = (t >> 4) << 2, tn = (t & 15) << 2;

  float acc[8][8];
#pragma unroll
  for (int i = 0; i < 8; i++)
#pragma unroll
    for (int j = 0; j < 8; j++) acc[i][j] = 0.f;

  float4 pa0 = *(const float4*)(Ag);
  float4 pa1 = *(const float4*)(Ag + 4);
  float4 pb0 = *(const float4*)(Bg);
  float4 pb1 = *(const float4*)(Bg + 4);

  for (int kt = 0; kt < klen; kt += 16) {
    __syncthreads();
    As[ah + 0][ar] = pa0.x; As[ah + 1][ar] = pa0.y;
    As[ah + 2][ar] = pa0.z; As[ah + 3][ar] = pa0.w;
    As[ah + 4][ar] = pa1.x; As[ah + 5][ar] = pa1.y;
    As[ah + 6][ar] = pa1.z; As[ah + 7][ar] = pa1.w;
    *(float4*)&Bs[br][bc] = pb0;
    *(float4*)&Bs[br][bc + 4] = pb1;
    __syncthreads();
    const int kt2 = (kt + 16 < klen) ? kt + 16 : kt;   // always-valid prefetch
    pa0 = *(const float4*)(Ag + kt2);
    pa1 = *(const float4*)(Ag + kt2 + 4);
    pb0 = *(const float4*)(Bg + (size_t)kt2 * N);
    pb1 = *(const float4*)(Bg + (size_t)kt2 * N + 4);
#pragma unroll
    for (int kk = 0; kk < 16; kk++) {
      const float4 a0 = *(const float4*)&As[kk][tm];
      const float4 a1 = *(const float4*)&As[kk][tm + 64];
      const float4 b0 = *(const float4*)&Bs[kk][tn];
      const float4 b1 = *(const float4*)&Bs[kk][tn + 64];
      const float av[8] = {a0.x, a0.y, a0.z, a0.w, a1.x, a1.y, a1.z, a1.w};
      const float bv[8] = {b0.x, b0.y, b0.z, b0.w, b1.x, b1.y, b1.z, b1.w};
#pragma unroll
      for (int i = 0; i < 8; i++)
#pragma unroll
        for (int j = 0; j < 8; j++) acc[i][j] += av[i] * bv[j];
    }
  }
#pragma unroll
  for (int i = 0; i < 8; i++) {
    const int row = m0 + ((i < 4) ? (tm + i) : (tm + 64 + i - 4));
#pragma unroll
    for (int jh = 0; jh < 2; jh++) {
      const int col = n0 + tn + jh * 64;
      float4 r;
      r.x = acc[i][jh * 4 + 0] + bias[col + 0];
      r.y = acc[i][jh * 4 + 1] + bias[col + 1];
      r.z = acc[i][jh * 4 + 2] + bias[col + 2];
      r.w = acc[i][jh * 4 + 3] + bias[col + 3];
      if (EPI == 1) { r.x = gelu_tanh(r.x); r.y = gelu_tanh(r.y); r.z = gelu_tanh(r.z); r.w = gelu_tanh(r.w); }
      *(float4*)&C[(size_t)row * N + col] = r;
    }
  }
}

// ================= gemm64 body: 128x64 tile, 256 thr, 8x4/thread =================
// bias may be null (split-K partials). Writes C[M,N] block (m0,n0), k-range [k0,k0+klen).
__device__ __forceinline__ void gemm64_body(
    const float* __restrict__ A, int Kld,
    const float* __restrict__ W, const float* __restrict__ bias,
    float* __restrict__ C, int N, int k0, int klen, int m0, int n0) {
  __shared__ float As[16][128];
  __shared__ float Bs[16][64];
  const int t = threadIdx.x;
  const int ar = t >> 1, ah = (t & 1) << 3;
  const int br = t >> 4, bc = (t & 15) << 2;
  const float* Ag = A + (size_t)(m0 + ar) * Kld + k0 + ah;
  const float* Bg = W + (size_t)(k0 + br) * N + n0 + bc;
  const int tm = (t >> 4) << 2, tn = (t & 15) << 2;

  float acc[8][4];
#pragma unroll
  for (int i = 0; i < 8; i++)
#pragma unroll
    for (int j = 0; j < 4; j++) acc[i][j] = 0.f;

  float4 pa0 = *(const float4*)(Ag);
  float4 pa1 = *(const float4*)(Ag + 4);
  float4 pb0 = *(const float4*)(Bg);

  for (int kt = 0; kt < klen; kt += 16) {
    __syncthreads();
    As[ah + 0][ar] = pa0.x; As[ah + 1][ar] = pa0.y;
    As[ah + 2][ar] = pa0.z; As[ah + 3][ar] = pa0.w;
    As[ah + 4][ar] = pa1.x; As[ah + 5][ar] = pa1.y;
    As[ah + 6][ar] = pa1.z; As[ah + 7][ar] = pa1.w;
    *(float4*)&Bs[br][bc] = pb0;
    __syncthreads();
    const int kt2 = (kt + 16 < klen) ? kt + 16 : kt;
    pa0 = *(const float4*)(Ag + kt2);
    pa1 = *(const float4*)(Ag + kt2 + 4);
    pb0 = *(const float4*)(Bg + (size_t)kt2 * N);
#pragma unroll
    for (int kk = 0; kk < 16; kk++) {
      const float4 a0 = *(const float4*)&As[kk][tm];
      const float4 a1 = *(const float4*)&As[kk][tm + 64];
      const float4 b0 = *(const float4*)&Bs[kk][tn];
      const float av[8] = {a0.x, a0.y, a0.z, a0.w, a1.x, a1.y, a1.z, a1.w};
      const float bv[4] = {b0.x, b0.y, b0.z, b0.w};
#pragma unroll
      for (int i = 0; i < 8; i++)
#pragma unroll
        for (int j = 0; j < 4; j++) acc[i][j] += av[i] * bv[j];
    }
  }
#pragma unroll
  for (int i = 0; i < 8; i++) {
    const int row = m0 + ((i < 4) ? (tm + i) : (tm + 64 + i - 4));
    const int col = n0 + tn;
    float4 r = {acc[i][0], acc[i][1], acc[i][2], acc[i][3]};
    if (bias) {
      r.x += bias[col + 0]; r.y += bias[col + 1];
      r.z += bias[col + 2]; r.w += bias[col + 3];
    }
    *(float4*)&C[(size_t)row * N + col] = r;
  }
}

// generic split-K wrapper: blockIdx.z selects k-chunk and output partial buffer
__global__ __launch_bounds__(256) void gemm64_splitk(
    const float* __restrict__ A, int Kld, const float* __restrict__ W,
    float* __restrict__ Cbase, size_t cstride, int N, int klen) {
  gemm64_body(A, Kld, W, nullptr, Cbase + (size_t)blockIdx.z * cstride, N,
              blockIdx.z * klen, klen, blockIdx.y << 7, blockIdx.x << 6);
}

// fused QKV: blockIdx.x = which*16 + ntile
__global__ __launch_bounds__(256) void qkv_gemm(
    const float* __restrict__ A,
    const float* __restrict__ Wq, const float* __restrict__ bq, float* __restrict__ Cq,
    const float* __restrict__ Wk, const float* __restrict__ bk, float* __restrict__ Ck,
    const float* __restrict__ Wv, const float* __restrict__ bv, float* __restrict__ Cv) {
  const int which = blockIdx.x >> 4;
  const int n0 = (blockIdx.x & 15) << 6;
  const float* W = (which == 0) ? Wq : (which == 1) ? Wk : Wv;
  const float* bias = (which == 0) ? bq : (which == 1) ? bk : bv;
  float* C = (which == 0) ? Cq : (which == 1) ? Ck : Cv;
  gemm64_body(A, DIM, W, bias, C, DIM, 0, DIM, blockIdx.y << 7, n0);
}

extern "C" void kernel_launch(void* const* d_in, const int* in_sizes, int n_in,
                              void* d_out, int out_size, void* d_ws, size_t ws_size,
                              hipStream_t stream) {
  const float* x     = (const float*)d_in[0];
  const float* freqs = (const float*)d_in[1];
  const float* c     = (const float*)d_in[2];
  const float* Wq = (const float*)d_in[3];  const float* bq = (const float*)d_in[4];
  const float* Wk = (const float*)d_in[5];  const float* bk = (const float*)d_in[6];
  const float* Wv = (const float*)d_in[7];  const float* bv = (const float*)d_in[8];
  const float* Wo = (const float*)d_in[9];  const float* bo = (const float*)d_in[10];
  const float* W1 = (const float*)d_in[11]; const float* b1 = (const float*)d_in[12];
  const float* W2 = (const float*)d_in[13]; const float* b2 = (const float*)d_in[14];
  const float* g1 = (const float*)d_in[15]; const float* be1 = (const float*)d_in[16];
  const float* g2 = (const float*)d_in[17]; const float* be2 = (const float*)d_in[18];
  const float* geo = (const float*)d_in[19];
  float* out = (float*)d_out;
  float* ws = (float*)d_ws;

  const size_t SZ = (size_t)WB * SEQ * DIM;   // 2M floats
  float* x_tan = ws + 0 * SZ;   // later: Wo part0, then FFN-down part0
  float* qb    = ws + 1 * SZ;   // q -> q_hyp (in place) -> later t2 (LN2 out)
  float* kb    = ws + 2 * SZ;   // k -> k_hyp            -> later FFN-down part1
  float* vb    = ws + 3 * SZ;   // v                     -> later Wo part1
  float* att   = ws + 4 * SZ;
  float* x_att = ws + 5 * SZ;
  float* h1    = ws + 6 * SZ;   // 4*SZ (FFN hidden)

  // 1. tangent LN1
  ln_tan_kernel<<<ROWS, 256, 0, stream>>>(x, c, g1, be1, x_tan);
  // 2. fused QKV projections (768 blocks = 3/CU)
  qkv_gemm<<<dim3(48, ROWS / 128), 256, 0, stream>>>(
      x_tan, Wq, bq, qb, Wk, bk, kb, Wv, bv, vb);
  // 3. RoPE + expmap0 (q,k in place)
  rope_expmap_kernel<<<ROWS, 256, 0, stream>>>(qb, kb, freqs, c);
  // 4. sliding-window Poincare attention
  attn_kernel<<<WB * NH * SEQ / 8, 256, 0, stream>>>(qb, kb, vb, c, geo, att);
  // 5. output projection, split-K=2 -> partials in x_tan (ws0) and vb (ws3)
  gemm64_splitk<<<dim3(DIM / 64, ROWS / 128, 2), 256, 0, stream>>>(
      att, DIM, Wo, x_tan, 3 * SZ, DIM, DIM / 2);
  // 6. x_att = mobius_add(x, expmap0(part0+part1+bo))
  expmobius_parts_kernel<<<ROWS, 256, 0, stream>>>(x, x_tan, vb, bo, c, x_att);
  // 7. tangent LN2 (t2 into qb)
  ln_tan_kernel<<<ROWS, 256, 0, stream>>>(x_att, c, g2, be2, qb);
  // 8. FFN up + gelu (512 blocks = 2/CU)
  gemm128<1><<<dim3(4 * DIM / 128, ROWS / 128), 256, 0, stream>>>(
      qb, DIM, W1, b1, h1, 4 * DIM, DIM);
  // 9. FFN down, split-K=2 -> partials in x_tan (ws0) and kb (ws2)
  gemm64_splitk<<<dim3(DIM / 64, ROWS / 128, 2), 256, 0, stream>>>(
      h1, 4 * DIM, W2, x_tan, 2 * SZ, DIM, 2 * DIM);
  // 10. out = mobius_add(x_att, expmap0(part0+part1+b2))
  expmobius_parts_kernel<<<ROWS, 256, 0, stream>>>(x_att, x_tan, kb, b2, c, out);
  (void)in_sizes; (void)n_in; (void)out_size; (void)ws_size;
}

// Round 3
// 461.898 us; speedup vs baseline: 2.3971x; 1.9568x over previous
//
#include <hip/hip_runtime.h>
#include <cmath>

// Problem constants (fixed by setup_inputs)
static constexpr int SEQ = 1024;
static constexpr int DIM = 1024;
static constexpr int NH  = 16;
static constexpr int DH  = 64;   // head dim
static constexpr int WB  = 2;    // batch
static constexpr int ROWS = WB * SEQ;           // 2048
__device__ static constexpr double D_EPS = 1e-7;

typedef __attribute__((ext_vector_type(8))) short short8v;   // 8 bf16 = 4 VGPR
typedef __attribute__((ext_vector_type(4))) float float4v;   // MFMA acc

// ---------------- bf16 hi/lo split helpers ----------------
__device__ __forceinline__ uint32_t bf16_hi_bits(float f) {   // RNE to bf16, bits in [15:0]
  uint32_t u = __float_as_uint(f);
  return (u + 0x7fffu + ((u >> 16) & 1u)) >> 16;
}
__device__ __forceinline__ uint32_t pack_hl(float f) {
  const uint32_t h = bf16_hi_bits(f);
  const float fh = __uint_as_float(h << 16);
  const uint32_t l = bf16_hi_bits(f - fh);
  return h | (l << 16);
}

// ---------------- reductions ----------------
__device__ __forceinline__ double wsum64(double v) {
#pragma unroll
  for (int m = 32; m >= 1; m >>= 1) v += __shfl_xor(v, m, 64);
  return v;
}

// ---------------- tangent-space layernorm chain (packed hi/lo output) ----------------
// out = logmap0(project(expmap0(LN(logmap0(x,c)), c)), c)   (per row of DIM)
__global__ __launch_bounds__(256) void ln_tan_kernel(
    const float* __restrict__ xin, const float* __restrict__ cb,
    const float* __restrict__ gamma, const float* __restrict__ beta,
    uint32_t* __restrict__ out) {
  __shared__ double sh[2][4];
  const int row = blockIdx.x;
  const int b = row / SEQ;
  const float* xr = xin + (size_t)row * DIM;
  const int t = threadIdx.x;
  float xv[4];
  double s0 = 0.0, s1 = 0.0;
#pragma unroll
  for (int i = 0; i < 4; i++) {
    xv[i] = xr[t + 256 * i];
    s0 += (double)xv[i];
    s1 += (double)xv[i] * (double)xv[i];
  }
  s0 = wsum64(s0); s1 = wsum64(s1);
  const int wid = t >> 6, lane = t & 63;
  if (lane == 0) { sh[0][wid] = s0; sh[1][wid] = s1; }
  __syncthreads();
  s0 = sh[0][0] + sh[0][1] + sh[0][2] + sh[0][3];
  s1 = sh[1][0] + sh[1][1] + sh[1][2] + sh[1][3];

  const double cc  = (double)cb[b];
  const double sqc = fmax(sqrt(cc), D_EPS);
  const double xn  = sqrt(s1);
  double a = 0.0;
  if (xn >= D_EPS) a = atanh(fmin(xn, 1.0 - D_EPS)) / sqc / fmax(xn, D_EPS);
  const double mu   = a * s0 / (double)DIM;
  const double var  = a * a * s1 / (double)DIM - mu * mu;
  const double invs = 1.0 / sqrt(var + 1e-6);

  double tv[4]; double s2 = 0.0;
#pragma unroll
  for (int i = 0; i < 4; i++) {
    const int col = t + 256 * i;
    tv[i] = (a * (double)xv[i] - mu) * invs * (double)gamma[col] + (double)beta[col];
    s2 += tv[i] * tv[i];
  }
  s2 = wsum64(s2);
  __syncthreads();
  if (lane == 0) sh[0][wid] = s2;
  __syncthreads();
  s2 = sh[0][0] + sh[0][1] + sh[0][2] + sh[0][3];

  const double tn = sqrt(s2);
  double C = 0.0;
  if (tn >= D_EPS) {
    const double safe_t = fmax(tn, D_EPS);
    const double mag2 = tanh(sqc * safe_t) / sqc;   // expmap0 magnitude
    const double en = mag2 * (tn / safe_t);         // ||e|| analytic
    const double pn = fmax(en, D_EPS);
    const double f  = (pn >= 1.0) ? (1.0 - D_EPS) / pn : 1.0;   // project
    const double yn = en * f;
    if (yn >= D_EPS) {
      const double mag3 = atanh(fmin(yn, 1.0 - D_EPS)) / sqc;   // logmap0
      C = (mag2 / safe_t) * f * (mag3 / fmax(yn, D_EPS));
    }
  }
  uint32_t* orow = out + (size_t)row * DIM;
#pragma unroll
  for (int i = 0; i < 4; i++) orow[t + 256 * i] = pack_hl((float)(tv[i] * C));
}

// ------- out = mobius_add(xb, expmap0(p0+p1+p2+p3+bias, c), c), partials stride SZ -------
__global__ __launch_bounds__(256) void expmobius_parts4_kernel(
    const float* __restrict__ xb, const float* __restrict__ parts,
    const float* __restrict__ bias, const float* __restrict__ cb,
    float* __restrict__ out) {
  __shared__ double sh[3][4];
  const size_t PSZ = (size_t)ROWS * DIM;
  const int row = blockIdx.x;
  const int b = row / SEQ;
  const float* xr = xb + (size_t)row * DIM;
  const float* p0r = parts + (size_t)row * DIM;
  const int t = threadIdx.x;
  float xv[4];
  double tv[4];
  double sx2 = 0.0, st2 = 0.0, sxt = 0.0;
#pragma unroll
  for (int i = 0; i < 4; i++) {
    const int col = t + 256 * i;
    xv[i] = xr[col];
    tv[i] = (double)p0r[col] + (double)p0r[col + PSZ] +
            (double)p0r[col + 2 * PSZ] + (double)p0r[col + 3 * PSZ] +
            (double)bias[col];
    sx2 += (double)xv[i] * (double)xv[i];
    st2 += tv[i] * tv[i];
    sxt += (double)xv[i] * tv[i];
  }
  sx2 = wsum64(sx2); st2 = wsum64(st2); sxt = wsum64(sxt);
  const int wid = t >> 6, lane = t & 63;
  if (lane == 0) { sh[0][wid] = sx2; sh[1][wid] = st2; sh[2][wid] = sxt; }
  __syncthreads();
  sx2 = sh[0][0] + sh[0][1] + sh[0][2] + sh[0][3];
  st2 = sh[1][0] + sh[1][1] + sh[1][2] + sh[1][3];
  sxt = sh[2][0] + sh[2][1] + sh[2][2] + sh[2][3];

  const double cc  = (double)cb[b];
  const double sqc = fmax(sqrt(cc), D_EPS);
  const double tn = sqrt(st2);
  double s = 0.0;
  if (tn >= D_EPS) {
    const double safe = fmax(tn, D_EPS);
    const double mag = tanh(sqc * safe) / sqc;      // expmap0
    const double en = mag * (tn / safe);
    const double pn = fmax(en, D_EPS);
    const double f  = (pn >= 1.0) ? (1.0 - D_EPS) / pn : 1.0;  // project
    s = (mag / safe) * f;                            // y_i = s * t_i
  }
  const double x2 = sx2, y2 = s * s * st2, xy = s * sxt;
  const double P   = 1.0 + 2.0 * cc * xy + cc * y2;
  const double Q   = 1.0 - cc * x2;
  const double den = fmax(1.0 + 2.0 * cc * xy + cc * cc * x2 * y2, D_EPS);
  const double num2 = P * P * x2 + Q * Q * y2 + 2.0 * P * Q * xy;
  const double rn  = sqrt(fmax(num2, 0.0)) / den;
  const double pn2 = fmax(rn, D_EPS);
  const double pf  = (pn2 >= 1.0) ? (1.0 - D_EPS) / pn2 : 1.0;  // project
  const double Pd = (P / den) * pf;
  const double Qd = (Q / den) * pf * s;
  float* orow = out + (size_t)row * DIM;
#pragma unroll
  for (int i = 0; i < 4; i++)
    orow[t + 256 * i] = (float)(Pd * (double)xv[i] + Qd * tv[i]);
}

// ---------------- RoPE + expmap0 per head, in place on q and k (fp32 buffers) ----------------
__global__ __launch_bounds__(256) void rope_expmap_kernel(
    float* __restrict__ q, float* __restrict__ k,
    const float* __restrict__ freqs, const float* __restrict__ cb) {
  const int row = blockIdx.x;           // b*SEQ + n
  const int b = row / SEQ, n = row % SEQ;
  const int t = threadIdx.x;
  const int h = t >> 4, j = t & 15;
  const int p1 = j, p2 = j + 16;        // pair indices in [0,32)
  const double f1 = (double)freqs[n * (DH / 2) + p1];
  const double f2 = (double)freqs[n * (DH / 2) + p2];
  const double c1 = cos(f1), s1 = sin(f1);
  const double c2 = cos(f2), s2 = sin(f2);
  const double cc  = (double)cb[b];
  const double sqc = fmax(sqrt(cc), D_EPS);
  const size_t base = (size_t)row * DIM + (size_t)h * DH;
  float* arrs[2] = {q, k};
#pragma unroll
  for (int a = 0; a < 2; a++) {
    float* p = arrs[a] + base;
    const double xr1 = p[p1], xi1 = p[p1 + 32];
    const double xr2 = p[p2], xi2 = p[p2 + 32];
    const double r1 = xr1 * c1 - xi1 * s1, i1 = xr1 * s1 + xi1 * c1;
    const double r2 = xr2 * c2 - xi2 * s2, i2 = xr2 * s2 + xi2 * c2;
    double nrm2 = r1 * r1 + i1 * i1 + r2 * r2 + i2 * i2;
#pragma unroll
    for (int m = 8; m >= 1; m >>= 1) nrm2 += __shfl_xor(nrm2, m, 16);
    const double vn = sqrt(nrm2);
    double sc = 0.0;
    if (vn >= D_EPS) {
      const double safe = fmax(vn, D_EPS);
      const double mag = tanh(sqc * safe) / sqc;
      const double en = mag * (vn / safe);
      const double pn = fmax(en, D_EPS);
      const double f  = (pn >= 1.0) ? (1.0 - D_EPS) / pn : 1.0;
      sc = (mag / safe) * f;
    }
    p[p1] = (float)(r1 * sc); p[p1 + 32] = (float)(i1 * sc);
    p[p2] = (float)(r2 * sc); p[p2 + 32] = (float)(i2 * sc);
  }
}

// ---------------- sliding-window Poincare attention (packed hi/lo output) ----------------
__global__ __launch_bounds__(256) void attn_kernel(
    const float* __restrict__ qh, const float* __restrict__ kh,
    const float* __restrict__ v, const float* __restrict__ cb,
    const float* __restrict__ geo, uint32_t* __restrict__ out) {
  __shared__ float qs[8][DH];
  const int g = threadIdx.x >> 5;       // group in block: 0..7
  const int w = threadIdx.x & 31;       // lane in group
  const int gid = blockIdx.x * 8 + g;   // (b*NH + h)*SEQ + n
  const int n = gid & (SEQ - 1);
  const int bh = gid >> 10;
  const int h = bh & (NH - 1);
  const int b = bh >> 4;
  const size_t qbase = ((size_t)(b * SEQ + n)) * DIM + (size_t)h * DH;
  qs[g][w] = qh[qbase + w];
  qs[g][w + 32] = qh[qbase + w + 32];
  __syncthreads();

  const double cc  = (double)cb[b];
  const double sqc = fmax(sqrt(cc), D_EPS);
  double q2p = (double)qs[g][w] * qs[g][w] + (double)qs[g][w + 32] * qs[g][w + 32];
#pragma unroll
  for (int m = 16; m >= 1; m >>= 1) q2p += __shfl_xor(q2p, m, 32);
  const double a2 = q2p;

  const int msrc = n - 31 + w;
  double y2 = 0.0, qy = 0.0;
  if (msrc >= 0) {
    const float* kr = kh + ((size_t)(b * SEQ + msrc)) * DIM + (size_t)h * DH;
#pragma unroll 8
    for (int d = 0; d < DH; d++) {
      const double kv = (double)kr[d];
      y2 += kv * kv;
      qy += (double)qs[g][d] * kv;
    }
  }
  const double ay = -qy;  // mobius_add(-q, k)
  const double P = 1.0 + 2.0 * cc * ay + cc * y2;
  const double Q = 1.0 - cc * a2;
  const double den = fmax(1.0 + 2.0 * cc * ay + cc * cc * a2 * y2, D_EPS);
  const double num2 = P * P * a2 + Q * Q * y2 + 2.0 * P * Q * ay;
  const double rn = sqrt(fmax(num2, 0.0)) / den;
  const double pn = fmax(rn, D_EPS);
  const double addn = (pn >= 1.0) ? (1.0 - D_EPS) * (rn / pn) : rn;  // project
  const double arg = fmin(sqc * addn, 1.0 - D_EPS);
  const double dist = 2.0 * atanh(arg) / sqc;
  const double logit = -(double)geo[h] * dist;

  double mx = logit;
#pragma unroll
  for (int m = 16; m >= 1; m >>= 1) mx = fmax(mx, __shfl_xor(mx, m, 32));
  const double e = exp(logit - mx);
  double se = e;
#pragma unroll
  for (int m = 16; m >= 1; m >>= 1) se += __shfl_xor(se, m, 32);
  const double p = e / se;

  double acc1 = 0.0, acc2 = 0.0;
  for (int wp = 0; wp < 32; wp++) {
    const double pw = __shfl(p, wp, 32);
    const int mp = n - 31 + wp;
    if (mp >= 0) {
      const float* vr = v + ((size_t)(b * SEQ + mp)) * DIM + (size_t)h * DH;
      acc1 += pw * (double)vr[w];
      acc2 += pw * (double)vr[w + 32];
    }
  }
  out[qbase + w] = pack_hl((float)acc1);
  out[qbase + w + 32] = pack_hl((float)acc2);
}

// ---------------- epilogue helper ----------------
__device__ __forceinline__ float gelu_tanh(float x) {
  const float x3 = x * x * x;
  return 0.5f * x * (1.0f + tanhf(0.7978845608028654f * (x + 0.044715f * x3)));
}

// ================= bf16x3 MFMA GEMM body: 128x128 tile, 256 thr, BK=32 =================
// A: packed hi/lo bf16 dwords [M x Kld]. W: fp32 [K x N], converted on the fly.
// C = A*W over k-range [k0, k0+klen). EPI: 0 = +bias fp32 out; 1 = +bias gelu packed out;
// 2 = fp32 partial out (no bias).
template <int EPI>
__device__ __forceinline__ void mfma_gemm_body(
    const uint32_t* __restrict__ Ap, int Kld,
    const float* __restrict__ Wf, const float* __restrict__ bias,
    void* __restrict__ Cout, int N, int k0, int klen, int m0, int n0) {
  // LDS: fragment-ordered bf16 tiles. Index (sub, lane, j) = (sub*64 + lane)*8 + j,
  // lane = q*16 + i  <->  A[m = sub*16 + i][k = q*8 + j]  (B: n = sub*16 + i).
  __shared__ __align__(16) short AsH[4096], AsL[4096], BsH[4096], BsL[4096];
  const int t = threadIdx.x;
  const int lane = t & 63, wave = t >> 6;
  const int wm = (wave >> 1) << 6, wn = (wave & 1) << 6;   // 64x64 per wave
  // --- A staging: thread t loads row am = t>>1, k-half akh = (t&1)*16 (16 packed dwords)
  const int am = t >> 1, akh = (t & 1) << 4;
  const uint32_t* Ag = Ap + (size_t)(m0 + am) * Kld + k0 + akh;
  const int as_ = am >> 4, ai = am & 15, aq0 = akh >> 3;
  short* awH0 = &AsH[((as_ << 6) + (aq0 << 4) + ai) << 3];
  short* awH1 = &AsH[((as_ << 6) + ((aq0 + 1) << 4) + ai) << 3];
  short* awL0 = &AsL[((as_ << 6) + (aq0 << 4) + ai) << 3];
  short* awL1 = &AsL[((as_ << 6) + ((aq0 + 1) << 4) + ai) << 3];
  // --- B staging: thread t owns col bn = t&127, k-group bkg = (t>>7)*16 (16 fp32, stride N)
  const int bn = t & 127, bkg = (t >> 7) << 4;
  const float* Bg = Wf + (size_t)(k0 + bkg) * N + n0 + bn;
  const int bs = bn >> 4, bi = bn & 15, bq0 = bkg >> 3;
  short* bwH0 = &BsH[((bs << 6) + (bq0 << 4) + bi) << 3];
  short* bwH1 = &BsH[((bs << 6) + ((bq0 + 1) << 4) + bi) << 3];
  short* bwL0 = &BsL[((bs << 6) + (bq0 << 4) + bi) << 3];
  short* bwL1 = &BsL[((bs << 6) + ((bq0 + 1) << 4) + bi) << 3];

  float4v acc[4][4];
#pragma unroll
  for (int i = 0; i < 4; i++)
#pragma unroll
    for (int j = 0; j < 4; j++) acc[i][j] = (float4v){0.f, 0.f, 0.f, 0.f};

  // prefetch first k-step
  uint32_t a[16];
  float bf[16];
  {
    const uint4* p = (const uint4*)Ag;
#pragma unroll
    for (int r = 0; r < 4; r++) { uint4 u = p[r]; a[4*r] = u.x; a[4*r+1] = u.y; a[4*r+2] = u.z; a[4*r+3] = u.w; }
#pragma unroll
    for (int r = 0; r < 16; r++) bf[r] = Bg[(size_t)r * N];
  }

  for (int kt = 0; kt < klen; kt += 32) {
    __syncthreads();
    // A: split packed pairs into hi-b128 / lo-b128 groups
    {
      uint4 h0, l0, h1, l1;
      uint32_t* hp0 = (uint32_t*)&h0; uint32_t* lp0 = (uint32_t*)&l0;
      uint32_t* hp1 = (uint32_t*)&h1; uint32_t* lp1 = (uint32_t*)&l1;
#pragma unroll
      for (int r = 0; r < 4; r++) {
        hp0[r] = (a[2*r] & 0xffffu) | (a[2*r+1] << 16);
        lp0[r] = (a[2*r] >> 16) | (a[2*r+1] & 0xffff0000u);
        hp1[r] = (a[8+2*r] & 0xffffu) | (a[8+2*r+1] << 16);
        lp1[r] = (a[8+2*r] >> 16) | (a[8+2*r+1] & 0xffff0000u);
      }
      *(uint4*)awH0 = h0; *(uint4*)awL0 = l0;
      *(uint4*)awH1 = h1; *(uint4*)awL1 = l1;
    }
    // B: convert fp32 -> hi/lo bf16
    {
      uint32_t hb[16], lb[16];
#pragma unroll
      for (int r = 0; r < 16; r++) {
        const uint32_t h = bf16_hi_bits(bf[r]);
        hb[r] = h;
        lb[r] = bf16_hi_bits(bf[r] - __uint_as_float(h << 16));
      }
      uint4 h0, l0, h1, l1;
      uint32_t* hp0 = (uint32_t*)&h0; uint32_t* lp0 = (uint32_t*)&l0;
      uint32_t* hp1 = (uint32_t*)&h1; uint32_t* lp1 = (uint32_t*)&l1;
#pragma unroll
      for (int r = 0; r < 4; r++) {
        hp0[r] = hb[2*r] | (hb[2*r+1] << 16);
        lp0[r] = lb[2*r] | (lb[2*r+1] << 16);
        hp1[r] = hb[8+2*r] | (hb[8+2*r+1] << 16);
        lp1[r] = lb[8+2*r] | (lb[8+2*r+1] << 16);
      }
      *(uint4*)bwH0 = h0; *(uint4*)bwL0 = l0;
      *(uint4*)bwH1 = h1; *(uint4*)bwL1 = l1;
    }
    __syncthreads();
    // prefetch next k-step (re-reads current on last iter; harmless)
    {
      const int ktn = (kt + 32 < klen) ? kt + 32 : kt;
      const uint4* p = (const uint4*)(Ag + ktn);
#pragma unroll
      for (int r = 0; r < 4; r++) { uint4 u = p[r]; a[4*r] = u.x; a[4*r+1] = u.y; a[4*r+2] = u.z; a[4*r+3] = u.w; }
      const float* bp = Bg + (size_t)ktn * N;
#pragma unroll
      for (int r = 0; r < 16; r++) bf[r] = bp[(size_t)r * N];
    }
    // compute: 48 MFMAs
    short8v aH[4], aL[4];
    const int ams = wm >> 4;   // wave's first m-subtile
#pragma unroll
    for (int im = 0; im < 4; im++) {
      aH[im] = *(const short8v*)&AsH[(((ams + im) << 6) + lane) << 3];
      aL[im] = *(const short8v*)&AsL[(((ams + im) << 6) + lane) << 3];
    }
    const int bns = wn >> 4;
#pragma unroll
    for (int in_ = 0; in_ < 4; in_++) {
      const short8v bH = *(const short8v*)&BsH[(((bns + in_) << 6) + lane) << 3];
      const short8v bL = *(const short8v*)&BsL[(((bns + in_) << 6) + lane) << 3];
#pragma unroll
      for (int im = 0; im < 4; im++) {
        acc[im][in_] = __builtin_amdgcn_mfma_f32_16x16x32_bf16(aH[im], bH, acc[im][in_], 0, 0, 0);
        acc[im][in_] = __builtin_amdgcn_mfma_f32_16x16x32_bf16(aH[im], bL, acc[im][in_], 0, 0, 0);
        acc[im][in_] = __builtin_amdgcn_mfma_f32_16x16x32_bf16(aL[im], bH, acc[im][in_], 0, 0, 0);
      }
    }
  }
  // epilogue: C/D layout col = lane&15, row = (lane>>4)*4 + r
  const int cq = lane >> 4, ci = lane & 15;
#pragma unroll
  for (int im = 0; im < 4; im++) {
    const int row = m0 + wm + im * 16 + cq * 4;
#pragma unroll
    for (int in_ = 0; in_ < 4; in_++) {
      const int col = n0 + wn + in_ * 16 + ci;
      if (EPI == 2) {
        float* C = (float*)Cout;
#pragma unroll
        for (int r = 0; r < 4; r++) C[(size_t)(row + r) * N + col] = acc[im][in_][r];
      } else {
        const float bv_ = bias[col];
        if (EPI == 0) {
          float* C = (float*)Cout;
#pragma unroll
          for (int r = 0; r < 4; r++) C[(size_t)(row + r) * N + col] = acc[im][in_][r] + bv_;
        } else {
          uint32_t* C = (uint32_t*)Cout;
#pragma unroll
          for (int r = 0; r < 4; r++)
            C[(size_t)(row + r) * N + col] = pack_hl(gelu_tanh(acc[im][in_][r] + bv_));
        }
      }
    }
  }
}

// fused QKV: blockIdx.x = which*8 + ntile
__global__ __launch_bounds__(256) void qkv_mfma(
    const uint32_t* __restrict__ Ap,
    const float* __restrict__ Wq, const float* __restrict__ bq, float* __restrict__ Cq,
    const float* __restrict__ Wk, const float* __restrict__ bk, float* __restrict__ Ck,
    const float* __restrict__ Wv, const float* __restrict__ bv, float* __restrict__ Cv) {
  const int which = blockIdx.x >> 3;
  const int n0 = (blockIdx.x & 7) << 7;
  const float* W = (which == 0) ? Wq : (which == 1) ? Wk : Wv;
  const float* bias = (which == 0) ? bq : (which == 1) ? bk : bv;
  float* C = (which == 0) ? Cq : (which == 1) ? Ck : Cv;
  mfma_gemm_body<0>(Ap, DIM, W, bias, C, DIM, 0, DIM, blockIdx.y << 7, n0);
}

// FFN up + gelu, packed output
__global__ __launch_bounds__(256) void ffn_up_mfma(
    const uint32_t* __restrict__ Ap, const float* __restrict__ W1,
    const float* __restrict__ b1, uint32_t* __restrict__ H) {
  mfma_gemm_body<1>(Ap, DIM, W1, b1, H, 4 * DIM, 0, DIM, blockIdx.y << 7, blockIdx.x << 7);
}

// split-K partial GEMM: blockIdx.z picks k-chunk and partial buffer
__global__ __launch_bounds__(256) void gemm_splitk_mfma(
    const uint32_t* __restrict__ Ap, int Kld, const float* __restrict__ W,
    float* __restrict__ Cbase, size_t cstride, int N, int klen) {
  mfma_gemm_body<2>(Ap, Kld, W, nullptr, Cbase + (size_t)blockIdx.z * cstride, N,
                    blockIdx.z * klen, klen, blockIdx.y << 7, blockIdx.x << 7);
}

extern "C" void kernel_launch(void* const* d_in, const int* in_sizes, int n_in,
                              void* d_out, int out_size, void* d_ws, size_t ws_size,
                              hipStream_t stream) {
  const float* x     = (const float*)d_in[0];
  const float* freqs = (const float*)d_in[1];
  const float* c     = (const float*)d_in[2];
  const float* Wq = (const float*)d_in[3];  const float* bq = (const float*)d_in[4];
  const float* Wk = (const float*)d_in[5];  const float* bk = (const float*)d_in[6];
  const float* Wv = (const float*)d_in[7];  const float* bv = (const float*)d_in[8];
  const float* Wo = (const float*)d_in[9];  const float* bo = (const float*)d_in[10];
  const float* W1 = (const float*)d_in[11]; const float* b1 = (const float*)d_in[12];
  const float* W2 = (const float*)d_in[13]; const float* b2 = (const float*)d_in[14];
  const float* g1 = (const float*)d_in[15]; const float* be1 = (const float*)d_in[16];
  const float* g2 = (const float*)d_in[17]; const float* be2 = (const float*)d_in[18];
  const float* geo = (const float*)d_in[19];
  float* out = (float*)d_out;
  float* ws = (float*)d_ws;

  const size_t SZ = (size_t)ROWS * DIM;   // 2M elements (8 MB per unit)
  // u0: x_tanP / Wo-partial0 / t2P      u1: q fp32 / Wo-p1 / FFN-p0
  // u2: k fp32 / Wo-p2 / FFN-p1        u3: v fp32 / Wo-p3 / FFN-p2
  // u4: attP / FFN-p3                  u5: x_att fp32
  // u6..u9: h1P (packed FFN hidden)
  uint32_t* x_tanP = (uint32_t*)(ws + 0 * SZ);
  float*    qb     = ws + 1 * SZ;
  float*    kb     = ws + 2 * SZ;
  float*    vb     = ws + 3 * SZ;
  uint32_t* attP   = (uint32_t*)(ws + 4 * SZ);
  float*    x_att  = ws + 5 * SZ;
  uint32_t* h1P    = (uint32_t*)(ws + 6 * SZ);
  float*    woP    = ws + 0 * SZ;   // Wo partials u0..u3
  float*    fdP    = ws + 1 * SZ;   // FFN-down partials u1..u4
  uint32_t* t2P    = (uint32_t*)(ws + 0 * SZ);

  // 1. tangent LN1 -> packed
  ln_tan_kernel<<<ROWS, 256, 0, stream>>>(x, c, g1, be1, x_tanP);
  // 2. fused QKV (384 blocks)
  qkv_mfma<<<dim3(24, ROWS / 128), 256, 0, stream>>>(
      x_tanP, Wq, bq, qb, Wk, bk, kb, Wv, bv, vb);
  // 3. RoPE + expmap0 (q,k in place)
  rope_expmap_kernel<<<ROWS, 256, 0, stream>>>(qb, kb, freqs, c);
  // 4. sliding-window Poincare attention -> packed
  attn_kernel<<<WB * NH * SEQ / 8, 256, 0, stream>>>(qb, kb, vb, c, geo, attP);
  // 5. output projection, split-K=4 -> partials u0..u3
  gemm_splitk_mfma<<<dim3(DIM / 128, ROWS / 128, 4), 256, 0, stream>>>(
      attP, DIM, Wo, woP, SZ, DIM, DIM / 4);
  // 6. x_att = mobius_add(x, expmap0(sum(partials)+bo))
  expmobius_parts4_kernel<<<ROWS, 256, 0, stream>>>(x, woP, bo, c, x_att);
  // 7. tangent LN2 -> packed (u0)
  ln_tan_kernel<<<ROWS, 256, 0, stream>>>(x_att, c, g2, be2, t2P);
  // 8. FFN up + gelu -> packed hidden (512 blocks)
  ffn_up_mfma<<<dim3(4 * DIM / 128, ROWS / 128), 256, 0, stream>>>(t2P, W1, b1, h1P);
  // 9. FFN down, split-K=4 -> partials u1..u4
  gemm_splitk_mfma<<<dim3(DIM / 128, ROWS / 128, 4), 256, 0, stream>>>(
      h1P, 4 * DIM, W2, fdP, SZ, DIM, DIM);
  // 10. out = mobius_add(x_att, expmap0(sum(partials)+b2))
  expmobius_parts4_kernel<<<ROWS, 256, 0, stream>>>(x_att, fdP, b2, c, out);
  (void)in_sizes; (void)n_in; (void)out_size; (void)ws_size;
}

// Round 5
// 430.641 us; speedup vs baseline: 2.5711x; 1.0726x over previous
//
#include <hip/hip_runtime.h>
#include <cmath>

// Problem constants (fixed by setup_inputs)
static constexpr int SEQ = 1024;
static constexpr int DIM = 1024;
static constexpr int NH  = 16;
static constexpr int DH  = 64;   // head dim
static constexpr int WB  = 2;    // batch
static constexpr int ROWS = WB * SEQ;           // 2048
__device__ static constexpr double D_EPS = 1e-7;

typedef unsigned short ushort_t;
typedef __attribute__((ext_vector_type(8))) short short8v;   // 8 bf16 = 4 VGPR
typedef __attribute__((ext_vector_type(4))) float float4v;   // MFMA acc

// ---------------- bf16 hi/lo split helpers ----------------
__device__ __forceinline__ uint32_t bf16_hi_bits(float f) {   // RNE to bf16, bits in [15:0]
  uint32_t u = __float_as_uint(f);
  return (u + 0x7fffu + ((u >> 16) & 1u)) >> 16;
}

// MFMA-fragment-tiled address for element (row=m, col=k) of an [M x Kld] operand
// (for B operands: row=n, col=k, Kld=K). Layout [m>>7][k>>5][s][q][i][j], tile=4096 elems.
__device__ __forceinline__ size_t tiled_addr(int row, int col, int Kld) {
  return ((size_t)(row >> 7) * (Kld >> 5) + (col >> 5)) * 4096
       + (size_t)((((row >> 4) & 7) << 9) + (((col >> 3) & 3) << 7) + ((row & 15) << 3) + (col & 7));
}
__device__ __forceinline__ void store_hl(ushort_t* __restrict__ hi, ushort_t* __restrict__ lo,
                                         size_t addr, float f) {
  const uint32_t hb = bf16_hi_bits(f);
  hi[addr] = (ushort_t)hb;
  lo[addr] = (ushort_t)bf16_hi_bits(f - __uint_as_float(hb << 16));
}

// ---------------- reductions ----------------
__device__ __forceinline__ double wsum64(double v) {
#pragma unroll
  for (int m = 32; m >= 1; m >>= 1) v += __shfl_xor(v, m, 64);
  return v;
}

// ---------------- weight conversion: fp32 [K x N] -> tiled hi/lo bf16 planes ----------------
__global__ __launch_bounds__(256) void conv_w_kernel(
    const float* __restrict__ W, ushort_t* __restrict__ hi, ushort_t* __restrict__ lo,
    int K, int N) {
  const int tid = blockIdx.x * 256 + threadIdx.x;   // K*N/8 threads
  const int n = tid % N;
  const int k0 = (tid / N) << 3;
  uint32_t hw[4], lw[4];
#pragma unroll
  for (int rp = 0; rp < 4; rp++) {
    uint32_t h2[2], l2[2];
#pragma unroll
    for (int e = 0; e < 2; e++) {
      const float f = W[(size_t)(k0 + rp * 2 + e) * N + n];
      const uint32_t hb = bf16_hi_bits(f);
      h2[e] = hb;
      l2[e] = bf16_hi_bits(f - __uint_as_float(hb << 16));
    }
    hw[rp] = h2[0] | (h2[1] << 16);
    lw[rp] = l2[0] | (l2[1] << 16);
  }
  const size_t addr = tiled_addr(n, k0, K);   // (row=n, col=k), multiple of 8
  *(uint4*)&hi[addr] = *(uint4*)hw;
  *(uint4*)&lo[addr] = *(uint4*)lw;
}

// ---------------- tangent-space layernorm chain (tiled hi/lo output) ----------------
__global__ __launch_bounds__(256) void ln_tan_kernel(
    const float* __restrict__ xin, const float* __restrict__ cb,
    const float* __restrict__ gamma, const float* __restrict__ beta,
    ushort_t* __restrict__ ohi, ushort_t* __restrict__ olo) {
  __shared__ double sh[2][4];
  const int row = blockIdx.x;
  const int b = row / SEQ;
  const float* xr = xin + (size_t)row * DIM;
  const int t = threadIdx.x;
  float xv[4];
  double s0 = 0.0, s1 = 0.0;
#pragma unroll
  for (int i = 0; i < 4; i++) {
    xv[i] = xr[t + 256 * i];
    s0 += (double)xv[i];
    s1 += (double)xv[i] * (double)xv[i];
  }
  s0 = wsum64(s0); s1 = wsum64(s1);
  const int wid = t >> 6, lane = t & 63;
  if (lane == 0) { sh[0][wid] = s0; sh[1][wid] = s1; }
  __syncthreads();
  s0 = sh[0][0] + sh[0][1] + sh[0][2] + sh[0][3];
  s1 = sh[1][0] + sh[1][1] + sh[1][2] + sh[1][3];

  const double cc  = (double)cb[b];
  const double sqc = fmax(sqrt(cc), D_EPS);
  const double xn  = sqrt(s1);
  double a = 0.0;
  if (xn >= D_EPS) a = atanh(fmin(xn, 1.0 - D_EPS)) / sqc / fmax(xn, D_EPS);
  const double mu   = a * s0 / (double)DIM;
  const double var  = a * a * s1 / (double)DIM - mu * mu;
  const double invs = 1.0 / sqrt(var + 1e-6);

  double tv[4]; double s2 = 0.0;
#pragma unroll
  for (int i = 0; i < 4; i++) {
    const int col = t + 256 * i;
    tv[i] = (a * (double)xv[i] - mu) * invs * (double)gamma[col] + (double)beta[col];
    s2 += tv[i] * tv[i];
  }
  s2 = wsum64(s2);
  __syncthreads();
  if (lane == 0) sh[0][wid] = s2;
  __syncthreads();
  s2 = sh[0][0] + sh[0][1] + sh[0][2] + sh[0][3];

  const double tn = sqrt(s2);
  double C = 0.0;
  if (tn >= D_EPS) {
    const double safe_t = fmax(tn, D_EPS);
    const double mag2 = tanh(sqc * safe_t) / sqc;   // expmap0 magnitude
    const double en = mag2 * (tn / safe_t);         // ||e|| analytic
    const double pn = fmax(en, D_EPS);
    const double f  = (pn >= 1.0) ? (1.0 - D_EPS) / pn : 1.0;   // project
    const double yn = en * f;
    if (yn >= D_EPS) {
      const double mag3 = atanh(fmin(yn, 1.0 - D_EPS)) / sqc;   // logmap0
      C = (mag2 / safe_t) * f * (mag3 / fmax(yn, D_EPS));
    }
  }
#pragma unroll
  for (int i = 0; i < 4; i++) {
    const int col = t + 256 * i;
    store_hl(ohi, olo, tiled_addr(row, col, DIM), (float)(tv[i] * C));
  }
}

// ------- out = mobius_add(xb, expmap0(p0+p1+p2+p3+bias, c), c) -------
// NOTE: may be called with out == xb (each thread reads its cols before writing them).
__global__ __launch_bounds__(256) void expmobius_parts4_kernel(
    const float* __restrict__ xb,
    const float* __restrict__ p0, const float* __restrict__ p1,
    const float* __restrict__ p2, const float* __restrict__ p3,
    const float* __restrict__ bias, const float* __restrict__ cb,
    float* __restrict__ out) {
  __shared__ double sh[3][4];
  const int row = blockIdx.x;
  const int b = row / SEQ;
  const size_t ro = (size_t)row * DIM;
  const int t = threadIdx.x;
  float xv[4];
  double tv[4];
  double sx2 = 0.0, st2 = 0.0, sxt = 0.0;
#pragma unroll
  for (int i = 0; i < 4; i++) {
    const int col = t + 256 * i;
    xv[i] = xb[ro + col];
    tv[i] = (double)p0[ro + col] + (double)p1[ro + col] +
            (double)p2[ro + col] + (double)p3[ro + col] + (double)bias[col];
    sx2 += (double)xv[i] * (double)xv[i];
    st2 += tv[i] * tv[i];
    sxt += (double)xv[i] * tv[i];
  }
  sx2 = wsum64(sx2); st2 = wsum64(st2); sxt = wsum64(sxt);
  const int wid = t >> 6, lane = t & 63;
  if (lane == 0) { sh[0][wid] = sx2; sh[1][wid] = st2; sh[2][wid] = sxt; }
  __syncthreads();
  sx2 = sh[0][0] + sh[0][1] + sh[0][2] + sh[0][3];
  st2 = sh[1][0] + sh[1][1] + sh[1][2] + sh[1][3];
  sxt = sh[2][0] + sh[2][1] + sh[2][2] + sh[2][3];

  const double cc  = (double)cb[b];
  const double sqc = fmax(sqrt(cc), D_EPS);
  const double tn = sqrt(st2);
  double s = 0.0;
  if (tn >= D_EPS) {
    const double safe = fmax(tn, D_EPS);
    const double mag = tanh(sqc * safe) / sqc;      // expmap0
    const double en = mag * (tn / safe);
    const double pn = fmax(en, D_EPS);
    const double f  = (pn >= 1.0) ? (1.0 - D_EPS) / pn : 1.0;  // project
    s = (mag / safe) * f;                            // y_i = s * t_i
  }
  const double x2 = sx2, y2 = s * s * st2, xy = s * sxt;
  const double P   = 1.0 + 2.0 * cc * xy + cc * y2;
  const double Q   = 1.0 - cc * x2;
  const double den = fmax(1.0 + 2.0 * cc * xy + cc * cc * x2 * y2, D_EPS);
  const double num2 = P * P * x2 + Q * Q * y2 + 2.0 * P * Q * xy;
  const double rn  = sqrt(fmax(num2, 0.0)) / den;
  const double pn2 = fmax(rn, D_EPS);
  const double pf  = (pn2 >= 1.0) ? (1.0 - D_EPS) / pn2 : 1.0;  // project
  const double Pd = (P / den) * pf;
  const double Qd = (Q / den) * pf * s;
#pragma unroll
  for (int i = 0; i < 4; i++)
    out[ro + t + 256 * i] = (float)(Pd * (double)xv[i] + Qd * tv[i]);
}

// ---------------- RoPE + expmap0 per head, in place on q and k (fp32 buffers) ----------------
__global__ __launch_bounds__(256) void rope_expmap_kernel(
    float* __restrict__ q, float* __restrict__ k,
    const float* __restrict__ freqs, const float* __restrict__ cb) {
  const int row = blockIdx.x;           // b*SEQ + n
  const int b = row / SEQ, n = row % SEQ;
  const int t = threadIdx.x;
  const int h = t >> 4, j = t & 15;
  const int p1 = j, p2 = j + 16;        // pair indices in [0,32)
  const double f1 = (double)freqs[n * (DH / 2) + p1];
  const double f2 = (double)freqs[n * (DH / 2) + p2];
  const double c1 = cos(f1), s1 = sin(f1);
  const double c2 = cos(f2), s2 = sin(f2);
  const double cc  = (double)cb[b];
  const double sqc = fmax(sqrt(cc), D_EPS);
  const size_t base = (size_t)row * DIM + (size_t)h * DH;
  float* arrs[2] = {q, k};
#pragma unroll
  for (int a = 0; a < 2; a++) {
    float* p = arrs[a] + base;
    const double xr1 = p[p1], xi1 = p[p1 + 32];
    const double xr2 = p[p2], xi2 = p[p2 + 32];
    const double r1 = xr1 * c1 - xi1 * s1, i1 = xr1 * s1 + xi1 * c1;
    const double r2 = xr2 * c2 - xi2 * s2, i2 = xr2 * s2 + xi2 * c2;
    double nrm2 = r1 * r1 + i1 * i1 + r2 * r2 + i2 * i2;
#pragma unroll
    for (int m = 8; m >= 1; m >>= 1) nrm2 += __shfl_xor(nrm2, m, 16);
    const double vn = sqrt(nrm2);
    double sc = 0.0;
    if (vn >= D_EPS) {
      const double safe = fmax(vn, D_EPS);
      const double mag = tanh(sqc * safe) / sqc;
      const double en = mag * (vn / safe);
      const double pn = fmax(en, D_EPS);
      const double f  = (pn >= 1.0) ? (1.0 - D_EPS) / pn : 1.0;
      sc = (mag / safe) * f;
    }
    p[p1] = (float)(r1 * sc); p[p1 + 32] = (float)(i1 * sc);
    p[p2] = (float)(r2 * sc); p[p2 + 32] = (float)(i2 * sc);
  }
}

// ---------------- sliding-window Poincare attention (tiled hi/lo output) ----------------
__global__ __launch_bounds__(256) void attn_kernel(
    const float* __restrict__ qh, const float* __restrict__ kh,
    const float* __restrict__ v, const float* __restrict__ cb,
    const float* __restrict__ geo,
    ushort_t* __restrict__ ohi, ushort_t* __restrict__ olo) {
  __shared__ float qs[8][DH];
  const int g = threadIdx.x >> 5;       // group in block: 0..7
  const int w = threadIdx.x & 31;       // lane in group
  const int gid = blockIdx.x * 8 + g;   // (b*NH + h)*SEQ + n
  const int n = gid & (SEQ - 1);
  const int bh = gid >> 10;
  const int h = bh & (NH - 1);
  const int b = bh >> 4;
  const int row = b * SEQ + n;
  const size_t qbase = (size_t)row * DIM + (size_t)h * DH;
  qs[g][w] = qh[qbase + w];
  qs[g][w + 32] = qh[qbase + w + 32];
  __syncthreads();

  const double cc  = (double)cb[b];
  const double sqc = fmax(sqrt(cc), D_EPS);
  double q2p = (double)qs[g][w] * qs[g][w] + (double)qs[g][w + 32] * qs[g][w + 32];
#pragma unroll
  for (int m = 16; m >= 1; m >>= 1) q2p += __shfl_xor(q2p, m, 32);
  const double a2 = q2p;

  const int msrc = n - 31 + w;
  double y2 = 0.0, qy = 0.0;
  if (msrc >= 0) {
    const float* kr = kh + ((size_t)(b * SEQ + msrc)) * DIM + (size_t)h * DH;
#pragma unroll 8
    for (int d = 0; d < DH; d++) {
      const double kv = (double)kr[d];
      y2 += kv * kv;
      qy += (double)qs[g][d] * kv;
    }
  }
  const double ay = -qy;  // mobius_add(-q, k)
  const double P = 1.0 + 2.0 * cc * ay + cc * y2;
  const double Q = 1.0 - cc * a2;
  const double den = fmax(1.0 + 2.0 * cc * ay + cc * cc * a2 * y2, D_EPS);
  const double num2 = P * P * a2 + Q * Q * y2 + 2.0 * P * Q * ay;
  const double rn = sqrt(fmax(num2, 0.0)) / den;
  const double pn = fmax(rn, D_EPS);
  const double addn = (pn >= 1.0) ? (1.0 - D_EPS) * (rn / pn) : rn;  // project
  const double arg = fmin(sqc * addn, 1.0 - D_EPS);
  const double dist = 2.0 * atanh(arg) / sqc;
  const double logit = -(double)geo[h] * dist;

  double mx = logit;
#pragma unroll
  for (int m = 16; m >= 1; m >>= 1) mx = fmax(mx, __shfl_xor(mx, m, 32));
  const double e = exp(logit - mx);
  double se = e;
#pragma unroll
  for (int m = 16; m >= 1; m >>= 1) se += __shfl_xor(se, m, 32);
  const double p = e / se;

  double acc1 = 0.0, acc2 = 0.0;
  for (int wp = 0; wp < 32; wp++) {
    const double pw = __shfl(p, wp, 32);
    const int mp = n - 31 + wp;
    if (mp >= 0) {
      const float* vr = v + ((size_t)(b * SEQ + mp)) * DIM + (size_t)h * DH;
      acc1 += pw * (double)vr[w];
      acc2 += pw * (double)vr[w + 32];
    }
  }
  const int col = h * DH + w;
  store_hl(ohi, olo, tiled_addr(row, col, DIM), (float)acc1);
  store_hl(ohi, olo, tiled_addr(row, col + 32, DIM), (float)acc2);
}

// ---------------- epilogue helper ----------------
__device__ __forceinline__ float gelu_tanh(float x) {
  const float x3 = x * x * x;
  return 0.5f * x * (1.0f + tanhf(0.7978845608028654f * (x + 0.044715f * x3)));
}

// ================= bf16x3 MFMA GEMM body: 128x128 tile, 256 thr, BK=32 =================
// A, B: tiled hi/lo bf16 planes (A: [M x Kld], B: [N x KB] tiled by (n,k)).
// C = A*B over k-range [k0, k0+klen). EPI: 0 = +bias fp32 out; 1 = +bias gelu tiled out;
// 2 = fp32 partial out (no bias). Staging = pure 16B copies (zero repack VALU).
template <int EPI>
__device__ __forceinline__ void mfma_gemm_body(
    const ushort_t* __restrict__ Ahi, const ushort_t* __restrict__ Alo, int Kld,
    const ushort_t* __restrict__ Bhi, const ushort_t* __restrict__ Blo, int KB,
    const float* __restrict__ bias, float* __restrict__ Cf,
    ushort_t* __restrict__ Chi, ushort_t* __restrict__ Clo, int KldOut,
    int N, int k0, int klen, int m0, int n0) {
  __shared__ __align__(16) short AsH[4096], AsL[4096], BsH[4096], BsL[4096];
  const int t = threadIdx.x;
  const int lane = t & 63, wave = t >> 6;
  const int wm = (wave >> 1) << 6, wn = (wave & 1) << 6;   // 64x64 per wave
  const size_t abase = (size_t)(m0 >> 7) * (Kld >> 5) * 4096;
  const size_t bbase = (size_t)(n0 >> 7) * (KB >> 5) * 4096;

  float4v acc[4][4];
#pragma unroll
  for (int i = 0; i < 4; i++)
#pragma unroll
    for (int j = 0; j < 4; j++) acc[i][j] = (float4v){0.f, 0.f, 0.f, 0.f};

  // prefetch tile 0 (each thread: chunks t and t+256 of each 8KB plane-tile)
  uint4 rah0, rah1, ral0, ral1, rbh0, rbh1, rbl0, rbl1;
  {
    const size_t at = abase + (size_t)(k0 >> 5) * 4096;
    const size_t bt = bbase + (size_t)(k0 >> 5) * 4096;
    rah0 = ((const uint4*)(Ahi + at))[t]; rah1 = ((const uint4*)(Ahi + at))[t + 256];
    ral0 = ((const uint4*)(Alo + at))[t]; ral1 = ((const uint4*)(Alo + at))[t + 256];
    rbh0 = ((const uint4*)(Bhi + bt))[t]; rbh1 = ((const uint4*)(Bhi + bt))[t + 256];
    rbl0 = ((const uint4*)(Blo + bt))[t]; rbl1 = ((const uint4*)(Blo + bt))[t + 256];
  }

  for (int kt = 0; kt < klen; kt += 32) {
    __syncthreads();
    ((uint4*)AsH)[t] = rah0; ((uint4*)AsH)[t + 256] = rah1;
    ((uint4*)AsL)[t] = ral0; ((uint4*)AsL)[t + 256] = ral1;
    ((uint4*)BsH)[t] = rbh0; ((uint4*)BsH)[t + 256] = rbh1;
    ((uint4*)BsL)[t] = rbl0; ((uint4*)BsL)[t + 256] = rbl1;
    __syncthreads();
    // prefetch next tile (re-reads current on last iter; harmless)
    {
      const int ktn = (kt + 32 < klen) ? kt + 32 : kt;
      const size_t at = abase + (size_t)((k0 + ktn) >> 5) * 4096;
      const size_t bt = bbase + (size_t)((k0 + ktn) >> 5) * 4096;
      rah0 = ((const uint4*)(Ahi + at))[t]; rah1 = ((const uint4*)(Ahi + at))[t + 256];
      ral0 = ((const uint4*)(Alo + at))[t]; ral1 = ((const uint4*)(Alo + at))[t + 256];
      rbh0 = ((const uint4*)(Bhi + bt))[t]; rbh1 = ((const uint4*)(Bhi + bt))[t + 256];
      rbl0 = ((const uint4*)(Blo + bt))[t]; rbl1 = ((const uint4*)(Blo + bt))[t + 256];
    }
    // compute: 48 MFMAs (bf16x3: HH + HL + LH)
    short8v aH[4], aL[4];
    const int ams = wm >> 4;
#pragma unroll
    for (int im = 0; im < 4; im++) {
      aH[im] = *(const short8v*)&AsH[(((ams + im) << 6) + lane) << 3];
      aL[im] = *(const short8v*)&AsL[(((ams + im) << 6) + lane) << 3];
    }
    const int bns = wn >> 4;
#pragma unroll
    for (int in_ = 0; in_ < 4; in_++) {
      const short8v bH = *(const short8v*)&BsH[(((bns + in_) << 6) + lane) << 3];
      const short8v bL = *(const short8v*)&BsL[(((bns + in_) << 6) + lane) << 3];
#pragma unroll
      for (int im = 0; im < 4; im++) {
        acc[im][in_] = __builtin_amdgcn_mfma_f32_16x16x32_bf16(aH[im], bH, acc[im][in_], 0, 0, 0);
        acc[im][in_] = __builtin_amdgcn_mfma_f32_16x16x32_bf16(aH[im], bL, acc[im][in_], 0, 0, 0);
        acc[im][in_] = __builtin_amdgcn_mfma_f32_16x16x32_bf16(aL[im], bH, acc[im][in_], 0, 0, 0);
      }
    }
  }
  // epilogue: C/D layout col = lane&15, row = (lane>>4)*4 + r
  const int cq = lane >> 4, ci = lane & 15;
#pragma unroll
  for (int im = 0; im < 4; im++) {
    const int row = m0 + wm + im * 16 + cq * 4;
#pragma unroll
    for (int in_ = 0; in_ < 4; in_++) {
      const int col = n0 + wn + in_ * 16 + ci;
      if (EPI == 2) {
#pragma unroll
        for (int r = 0; r < 4; r++) Cf[(size_t)(row + r) * N + col] = acc[im][in_][r];
      } else if (EPI == 0) {
        const float bv_ = bias[col];
#pragma unroll
        for (int r = 0; r < 4; r++) Cf[(size_t)(row + r) * N + col] = acc[im][in_][r] + bv_;
      } else {
        const float bv_ = bias[col];
#pragma unroll
        for (int r = 0; r < 4; r++)
          store_hl(Chi, Clo, tiled_addr(row + r, col, KldOut),
                   gelu_tanh(acc[im][in_][r] + bv_));
      }
    }
  }
}

// fused QKV: blockIdx.x = which*8 + ntile
__global__ __launch_bounds__(256) void qkv_mfma(
    const ushort_t* __restrict__ Ahi, const ushort_t* __restrict__ Alo,
    const ushort_t* __restrict__ Whi, const ushort_t* __restrict__ Wlo,  // Wq,Wk,Wv planes packed at 1M offsets
    const float* __restrict__ bq, const float* __restrict__ bk, const float* __restrict__ bv,
    float* __restrict__ Cq, float* __restrict__ Ck, float* __restrict__ Cv) {
  const int which = blockIdx.x >> 3;
  const int n0 = (blockIdx.x & 7) << 7;
  const size_t woff = (size_t)which * (1u << 20);
  const float* bias = (which == 0) ? bq : (which == 1) ? bk : bv;
  float* C = (which == 0) ? Cq : (which == 1) ? Ck : Cv;
  mfma_gemm_body<0>(Ahi, Alo, DIM, Whi + woff, Wlo + woff, DIM, bias, C,
                    nullptr, nullptr, 0, DIM, 0, DIM, blockIdx.y << 7, n0);
}

// FFN up + gelu, tiled hi/lo hidden output
__global__ __launch_bounds__(256) void ffn_up_mfma(
    const ushort_t* __restrict__ Ahi, const ushort_t* __restrict__ Alo,
    const ushort_t* __restrict__ W1hi, const ushort_t* __restrict__ W1lo,
    const float* __restrict__ b1, ushort_t* __restrict__ Hhi, ushort_t* __restrict__ Hlo) {
  mfma_gemm_body<1>(Ahi, Alo, DIM, W1hi, W1lo, DIM, b1, nullptr, Hhi, Hlo, 4 * DIM,
                    4 * DIM, 0, DIM, blockIdx.y << 7, blockIdx.x << 7);
}

// split-K partial GEMM: blockIdx.z picks k-chunk and partial buffer
__global__ __launch_bounds__(256) void gemm_splitk_mfma(
    const ushort_t* __restrict__ Ahi, const ushort_t* __restrict__ Alo, int Kld,
    const ushort_t* __restrict__ Bhi, const ushort_t* __restrict__ Blo, int KB,
    float* __restrict__ C0, float* __restrict__ C1,
    float* __restrict__ C2, float* __restrict__ C3, int N, int klen) {
  const int z = blockIdx.z;
  float* C = (z == 0) ? C0 : (z == 1) ? C1 : (z == 2) ? C2 : C3;
  mfma_gemm_body<2>(Ahi, Alo, Kld, Bhi, Blo, KB, nullptr, C, nullptr, nullptr, 0,
                    N, z * klen, klen, blockIdx.y << 7, blockIdx.x << 7);
}

extern "C" void kernel_launch(void* const* d_in, const int* in_sizes, int n_in,
                              void* d_out, int out_size, void* d_ws, size_t ws_size,
                              hipStream_t stream) {
  const float* x     = (const float*)d_in[0];
  const float* freqs = (const float*)d_in[1];
  const float* c     = (const float*)d_in[2];
  const float* Wq = (const float*)d_in[3];  const float* bq = (const float*)d_in[4];
  const float* Wk = (const float*)d_in[5];  const float* bk = (const float*)d_in[6];
  const float* Wv = (const float*)d_in[7];  const float* bv = (const float*)d_in[8];
  const float* Wo = (const float*)d_in[9];  const float* bo = (const float*)d_in[10];
  const float* W1 = (const float*)d_in[11]; const float* b1 = (const float*)d_in[12];
  const float* W2 = (const float*)d_in[13]; const float* b2 = (const float*)d_in[14];
  const float* g1 = (const float*)d_in[15]; const float* be1 = (const float*)d_in[16];
  const float* g2 = (const float*)d_in[17]; const float* be2 = (const float*)d_in[18];
  const float* geo = (const float*)d_in[19];
  float* out = (float*)d_out;
  float* ws = (float*)d_ws;

  const size_t SZ = (size_t)ROWS * DIM;       // 2M floats per unit (8 MB) = 4M ushorts
  const size_t PL = SZ;                       // ushorts per activation PLANE (= half unit)
  const uint32_t M1 = 1u << 20;               // 1M ushorts (one 1024x1024 weight plane)
  auto us = [&](int i) { return (ushort_t*)(ws + (size_t)i * SZ); };

  // Unit plan (x_att lives in d_out):
  // u0: x_tanP hi+lo  -> Wo part0 -> h1 hi (low half)
  // u1: qb            -> Wo part1 -> h1 hi (high half)
  // u2: kb            -> Wo part2 -> h1 lo (low half)
  // u3: vb            -> Wo part3 -> h1 lo (high half)
  // u4: attP hi+lo    -> t2P hi+lo -> FFN part0
  // u5: Wq/Wk/Wv/Wo hi planes -> W2 hi      u6: same, lo planes -> W2 lo
  // u7: W1 hi -> FFN part1    u8: W1 lo -> FFN part2    u9: FFN part3
  ushort_t* xt_hi = us(0);           ushort_t* xt_lo = us(0) + PL;
  float* qb = ws + 1 * SZ; float* kb = ws + 2 * SZ; float* vb = ws + 3 * SZ;
  ushort_t* at_hi = us(4);           ushort_t* at_lo = us(4) + PL;
  ushort_t* qkvo_hi = us(5);         ushort_t* qkvo_lo = us(6);
  ushort_t* w1_hi = us(7);           ushort_t* w1_lo = us(8);
  ushort_t* w2_hi = us(5);           ushort_t* w2_lo = us(6);
  ushort_t* t2_hi = us(4);           ushort_t* t2_lo = us(4) + PL;
  ushort_t* h1_hi = us(0);           ushort_t* h1_lo = us(2);   // each spans 2 units
  float* x_att = out;

  // 0. weight conversion (QKV+Wo -> u5/u6, W1 -> u7/u8)
  conv_w_kernel<<<512, 256, 0, stream>>>(Wq, qkvo_hi + 0 * M1, qkvo_lo + 0 * M1, DIM, DIM);
  conv_w_kernel<<<512, 256, 0, stream>>>(Wk, qkvo_hi + 1 * M1, qkvo_lo + 1 * M1, DIM, DIM);
  conv_w_kernel<<<512, 256, 0, stream>>>(Wv, qkvo_hi + 2 * M1, qkvo_lo + 2 * M1, DIM, DIM);
  conv_w_kernel<<<512, 256, 0, stream>>>(Wo, qkvo_hi + 3 * M1, qkvo_lo + 3 * M1, DIM, DIM);
  conv_w_kernel<<<2048, 256, 0, stream>>>(W1, w1_hi, w1_lo, DIM, 4 * DIM);
  // 1. tangent LN1 -> tiled planes (u0)
  ln_tan_kernel<<<ROWS, 256, 0, stream>>>(x, c, g1, be1, xt_hi, xt_lo);
  // 2. fused QKV (384 blocks)
  qkv_mfma<<<dim3(24, ROWS / 128), 256, 0, stream>>>(
      xt_hi, xt_lo, qkvo_hi, qkvo_lo, bq, bk, bv, qb, kb, vb);
  // 3. RoPE + expmap0 (q,k in place)
  rope_expmap_kernel<<<ROWS, 256, 0, stream>>>(qb, kb, freqs, c);
  // 4. sliding-window Poincare attention -> tiled planes (u4)
  attn_kernel<<<WB * NH * SEQ / 8, 256, 0, stream>>>(qb, kb, vb, c, geo, at_hi, at_lo);
  // 5. output projection, split-K=4 -> partials u0..u3
  gemm_splitk_mfma<<<dim3(DIM / 128, ROWS / 128, 4), 256, 0, stream>>>(
      at_hi, at_lo, DIM, qkvo_hi + 3 * M1, qkvo_lo + 3 * M1, DIM,
      ws + 0 * SZ, ws + 1 * SZ, ws + 2 * SZ, ws + 3 * SZ, DIM, DIM / 4);
  // 5b. W2 conversion into freed u5/u6 (stream-serialized after step 5)
  conv_w_kernel<<<2048, 256, 0, stream>>>(W2, w2_hi, w2_lo, 4 * DIM, DIM);
  // 6. x_att = mobius_add(x, expmap0(sum(partials)+bo))  [x_att in d_out]
  expmobius_parts4_kernel<<<ROWS, 256, 0, stream>>>(
      x, ws + 0 * SZ, ws + 1 * SZ, ws + 2 * SZ, ws + 3 * SZ, bo, c, x_att);
  // 7. tangent LN2 -> tiled planes (u4, over dead attP)
  ln_tan_kernel<<<ROWS, 256, 0, stream>>>(x_att, c, g2, be2, t2_hi, t2_lo);
  // 8. FFN up + gelu -> tiled hidden planes (u0-u3, over dead Wo partials)
  ffn_up_mfma<<<dim3(4 * DIM / 128, ROWS / 128), 256, 0, stream>>>(
      t2_hi, t2_lo, w1_hi, w1_lo, b1, h1_hi, h1_lo);
  // 9. FFN down, split-K=4 -> partials u4,u7,u8,u9 (over dead t2/W1 planes)
  gemm_splitk_mfma<<<dim3(DIM / 128, ROWS / 128, 4), 256, 0, stream>>>(
      h1_hi, h1_lo, 4 * DIM, w2_hi, w2_lo, 4 * DIM,
      ws + 4 * SZ, ws + 7 * SZ, ws + 8 * SZ, ws + 9 * SZ, DIM, DIM);
  // 10. out = mobius_add(x_att, expmap0(sum(partials)+b2))  [out == x_att: safe]
  expmobius_parts4_kernel<<<ROWS, 256, 0, stream>>>(
      x_att, ws + 4 * SZ, ws + 7 * SZ, ws + 8 * SZ, ws + 9 * SZ, b2, c, out);
  (void)in_sizes; (void)n_in; (void)out_size; (void)ws_size;
}